// Round 1
// baseline (698.498 us; speedup 1.0000x reference)
//
#include <hip/hip_runtime.h>

typedef unsigned short u16;
typedef unsigned int u32;
typedef __attribute__((ext_vector_type(8))) short short8;   // 8 bf16 (4 VGPRs)
typedef __attribute__((ext_vector_type(4))) float f32x4;

struct __align__(8) us4 { u16 x, y, z, w; };

__device__ __forceinline__ float bf1(u16 v){ return __uint_as_float(((u32)v) << 16); }
__device__ __forceinline__ float bflo(u32 u){ return __uint_as_float(u << 16); }
__device__ __forceinline__ float bfhi(u32 u){ return __uint_as_float(u & 0xFFFF0000u); }
__device__ __forceinline__ u16 fbf(float f){
    u32 u = __float_as_uint(f);
    return (u16)((u + 0x7FFFu + ((u >> 16) & 1u)) >> 16);   // RTNE
}
__device__ __forceinline__ float gelu_exact(float x){
    return 0.5f * x * (1.0f + erff(x * 0.70710678118654752f));
}
__device__ __forceinline__ void unp8(uint4 u, float* f){
    f[0]=bflo(u.x); f[1]=bfhi(u.x); f[2]=bflo(u.y); f[3]=bfhi(u.y);
    f[4]=bflo(u.z); f[5]=bfhi(u.z); f[6]=bflo(u.w); f[7]=bfhi(u.w);
}
__device__ __forceinline__ uint4 pack8(float4 a, float4 b){
    uint4 u;
    u.x = (u32)fbf(a.x) | ((u32)fbf(a.y) << 16);
    u.y = (u32)fbf(a.z) | ((u32)fbf(a.w) << 16);
    u.z = (u32)fbf(b.x) | ((u32)fbf(b.y) << 16);
    u.w = (u32)fbf(b.z) | ((u32)fbf(b.w) << 16);
    return u;
}

// ---------------------------------------------------------------------------
// ws layout (bytes) — total 61,616,644 (R6-proven size):
//  0          : h1b  [47104x384] bf16  (36,175,872)
//  36175872   : redb [47104x256] bf16  (24,117,248)  red -> "updated" in place
//  60293120   : Wb   bf16 weights, wconv order (661,760 elems = 1,323,520 B)
//  61616640   : lossAcc (f32)
// ---------------------------------------------------------------------------

__global__ __launch_bounds__(256) void wconv(
    const float* __restrict__ W1, const float* __restrict__ W2,
    const float* __restrict__ Wq, const float* __restrict__ Wk,
    const float* __restrict__ Wv, const float* __restrict__ Wo,
    const float* __restrict__ Wp, u16* __restrict__ dst)
{
    const int i = blockIdx.x * 256 + threadIdx.x;   // grid exactly 661760
    const float* s; int o;
    if      (i < 294912) { s = W1; o = i; }
    else if (i < 393216) { s = W2; o = i - 294912; }
    else if (i < 458752) { s = Wq; o = i - 393216; }
    else if (i < 524288) { s = Wk; o = i - 458752; }
    else if (i < 589824) { s = Wv; o = i - 524288; }
    else if (i < 655360) { s = Wo; o = i - 589824; }
    else                 { s = Wp; o = i - 655360; }
    dst[i] = fbf(s[o]);
}

// ---------------------------------------------------------------------------
// GEMM1 (fused gather): C[N,384] bf16 = gelu(sec @ W1^T + b1).
// ---------------------------------------------------------------------------
__global__ __launch_bounds__(256) void gemm1_kernel(
    const float* __restrict__ cls, const int* __restrict__ mask,
    const float* __restrict__ missing, const u16* __restrict__ W,
    const float* __restrict__ bias, u16* __restrict__ C)
{
    const int K = 768, M = 384;
    __shared__ u16 As[128 * 40];
    __shared__ u16 Bs[128 * 40];
    const int tid = threadIdx.x;
    const int w = tid >> 6, lane = tid & 63;
    const int nBase = blockIdx.y * 128, mBase = blockIdx.x * 128;
    const int wr = w >> 1, wc = w & 1;
    const int r0 = tid >> 2;
    const int co = (tid & 3) * 8;
    const int frow = lane & 15, quad = lane >> 4;

    const int rowA0 = nBase + r0, rowA1 = nBase + r0 + 64;
    const float* ap0 = (mask[rowA0] > 0) ? cls + (size_t)rowA0 * 768
                                         : missing + (size_t)(rowA0 % 23) * 768;
    const float* ap1 = (mask[rowA1] > 0) ? cls + (size_t)rowA1 * 768
                                         : missing + (size_t)(rowA1 % 23) * 768;
    const u16* bp0 = W + (size_t)(mBase + r0) * K;
    const u16* bp1 = W + (size_t)(mBase + r0 + 64) * K;

    f32x4 acc[4][4];
#pragma unroll
    for (int mt = 0; mt < 4; ++mt)
#pragma unroll
        for (int nt = 0; nt < 4; ++nt) acc[mt][nt] = f32x4{0.f, 0.f, 0.f, 0.f};

    float4 a0a = *(const float4*)(ap0 + co), a0b = *(const float4*)(ap0 + co + 4);
    float4 a1a = *(const float4*)(ap1 + co), a1b = *(const float4*)(ap1 + co + 4);
    uint4 pb0 = *(const uint4*)(bp0 + co), pb1 = *(const uint4*)(bp1 + co);

    for (int k0 = 0; k0 < K; k0 += 32) {
        __syncthreads();
        *(uint4*)(As + r0 * 40 + co) = pack8(a0a, a0b);
        *(uint4*)(As + (r0 + 64) * 40 + co) = pack8(a1a, a1b);
        *(uint4*)(Bs + r0 * 40 + co) = pb0;
        *(uint4*)(Bs + (r0 + 64) * 40 + co) = pb1;
        __syncthreads();
        if (k0 + 32 < K) {
            const int kn = k0 + 32 + co;
            a0a = *(const float4*)(ap0 + kn); a0b = *(const float4*)(ap0 + kn + 4);
            a1a = *(const float4*)(ap1 + kn); a1b = *(const float4*)(ap1 + kn + 4);
            pb0 = *(const uint4*)(bp0 + kn);  pb1 = *(const uint4*)(bp1 + kn);
        }
        short8 af[4], bfv[4];
#pragma unroll
        for (int mt = 0; mt < 4; ++mt)
            af[mt] = *(const short8*)(As + (wr * 64 + mt * 16 + frow) * 40 + quad * 8);
#pragma unroll
        for (int nt = 0; nt < 4; ++nt)
            bfv[nt] = *(const short8*)(Bs + (wc * 64 + nt * 16 + frow) * 40 + quad * 8);
#pragma unroll
        for (int mt = 0; mt < 4; ++mt)
#pragma unroll
            for (int nt = 0; nt < 4; ++nt)
                acc[mt][nt] = __builtin_amdgcn_mfma_f32_16x16x32_bf16(
                    af[mt], bfv[nt], acc[mt][nt], 0, 0, 0);
    }

#pragma unroll
    for (int nt = 0; nt < 4; ++nt) {
        const int col = mBase + wc * 64 + nt * 16 + frow;
        const float bv = bias[col];
#pragma unroll
        for (int mt = 0; mt < 4; ++mt)
#pragma unroll
            for (int reg = 0; reg < 4; ++reg) {
                const int row = nBase + wr * 64 + mt * 16 + quad * 4 + reg;
                C[(size_t)row * M + col] = fbf(gelu_exact(acc[mt][nt][reg] + bv));
            }
    }
}

// ---------------------------------------------------------------------------
// GEMM2: C[N,M] bf16 = gelu(A @ W^T + bias), bf16 inputs.
// ---------------------------------------------------------------------------
__global__ __launch_bounds__(256) void gemm_bt(
    const u16* __restrict__ A, const u16* __restrict__ W,
    const float* __restrict__ bias, u16* __restrict__ C, int K, int M)
{
    __shared__ u16 As[128 * 40];
    __shared__ u16 Bs[128 * 40];
    const int tid = threadIdx.x;
    const int w = tid >> 6, lane = tid & 63;
    const int nBase = blockIdx.y * 128, mBase = blockIdx.x * 128;
    const int wr = w >> 1, wc = w & 1;
    const int r0 = tid >> 2;
    const int co = (tid & 3) * 8;
    const int frow = lane & 15, quad = lane >> 4;

    f32x4 acc[4][4];
#pragma unroll
    for (int mt = 0; mt < 4; ++mt)
#pragma unroll
        for (int nt = 0; nt < 4; ++nt) acc[mt][nt] = f32x4{0.f, 0.f, 0.f, 0.f};

    uint4 pa0 = *(const uint4*)(A + (size_t)(nBase + r0) * K + co);
    uint4 pa1 = *(const uint4*)(A + (size_t)(nBase + r0 + 64) * K + co);
    uint4 pb0 = *(const uint4*)(W + (size_t)(mBase + r0) * K + co);
    uint4 pb1 = *(const uint4*)(W + (size_t)(mBase + r0 + 64) * K + co);

    for (int k0 = 0; k0 < K; k0 += 32) {
        __syncthreads();
        *(uint4*)(As + r0 * 40 + co) = pa0;
        *(uint4*)(As + (r0 + 64) * 40 + co) = pa1;
        *(uint4*)(Bs + r0 * 40 + co) = pb0;
        *(uint4*)(Bs + (r0 + 64) * 40 + co) = pb1;
        __syncthreads();
        if (k0 + 32 < K) {
            const int kn = k0 + 32 + co;
            pa0 = *(const uint4*)(A + (size_t)(nBase + r0) * K + kn);
            pa1 = *(const uint4*)(A + (size_t)(nBase + r0 + 64) * K + kn);
            pb0 = *(const uint4*)(W + (size_t)(mBase + r0) * K + kn);
            pb1 = *(const uint4*)(W + (size_t)(mBase + r0 + 64) * K + kn);
        }
        short8 af[4], bfv[4];
#pragma unroll
        for (int mt = 0; mt < 4; ++mt)
            af[mt] = *(const short8*)(As + (wr * 64 + mt * 16 + frow) * 40 + quad * 8);
#pragma unroll
        for (int nt = 0; nt < 4; ++nt)
            bfv[nt] = *(const short8*)(Bs + (wc * 64 + nt * 16 + frow) * 40 + quad * 8);
#pragma unroll
        for (int mt = 0; mt < 4; ++mt)
#pragma unroll
            for (int nt = 0; nt < 4; ++nt)
                acc[mt][nt] = __builtin_amdgcn_mfma_f32_16x16x32_bf16(
                    af[mt], bfv[nt], acc[mt][nt], 0, 0, 0);
    }

#pragma unroll
    for (int nt = 0; nt < 4; ++nt) {
        const int col = mBase + wc * 64 + nt * 16 + frow;
        const float bv = bias[col];
#pragma unroll
        for (int mt = 0; mt < 4; ++mt)
#pragma unroll
            for (int reg = 0; reg < 4; ++reg) {
                const int row = nBase + wr * 64 + mt * 16 + quad * 4 + reg;
                C[(size_t)row * M + col] = fbf(gelu_exact(acc[mt][nt][reg] + bv));
            }
    }
}

// ---- LayerNorm over 256, in-place bf16, 1 wave per row ----
__global__ __launch_bounds__(256) void ln_kernel(
    u16* __restrict__ X, const float* __restrict__ g, const float* __restrict__ b)
{
    const int w = threadIdx.x >> 6, lane = threadIdx.x & 63;
    const size_t row = (size_t)blockIdx.x * 4 + w;
    u16* xp = X + row * 256 + lane * 4;
    us4 uv = *(const us4*)xp;
    float x0 = bf1(uv.x), x1 = bf1(uv.y), x2 = bf1(uv.z), x3 = bf1(uv.w);
    float s = x0 + x1 + x2 + x3;
#pragma unroll
    for (int m = 32; m; m >>= 1) s += __shfl_xor(s, m);
    const float mu = s * (1.f / 256.f);
    const float d0 = x0 - mu, d1 = x1 - mu, d2 = x2 - mu, d3 = x3 - mu;
    float vs = d0 * d0 + d1 * d1 + d2 * d2 + d3 * d3;
#pragma unroll
    for (int m = 32; m; m >>= 1) vs += __shfl_xor(vs, m);
    const float rs = rsqrtf(vs * (1.f / 256.f) + 1e-5f);
    const float4 gv = *(const float4*)(g + lane * 4);
    const float4 bv = *(const float4*)(b + lane * 4);
    us4 o;
    o.x = fbf(d0 * rs * gv.x + bv.x);
    o.y = fbf(d1 * rs * gv.y + bv.y);
    o.z = fbf(d2 * rs * gv.z + bv.z);
    o.w = fbf(d3 * rs * gv.w + bv.w);
    *(us4*)xp = o;
}

// ---------------------------------------------------------------------------
// attn1 per batch element: QKV (MFMA) + softmax + ctx + Wo (MFMA) + scatter
// of missing rows into global redb (in place).
// R7 restructure: probs stay in f32 registers (no s_p buffer, no bf16
// roundtrip); ctx computed by the 184 softmax threads with vectorized b128
// v-reads and written into the thread's OWN q-slice of s_rq (private ->
// no barrier between softmax and ctx). LDS 44.9 KB -> 36.1 KB => 4 blocks/CU.
// ---------------------------------------------------------------------------
#define QSTR 264
__global__ __launch_bounds__(256) void attn1_kernel(
    u16* __restrict__ redb, const int* __restrict__ mask,
    const u16* __restrict__ Wqkvb,                       // [768][256]: q,k,v stacked
    const float* __restrict__ bq, const float* __restrict__ bk,
    const float* __restrict__ bv, const u16* __restrict__ Wob,
    const float* __restrict__ bo)
{
    __shared__ __align__(16) unsigned char SM[36064];
    u16* s_rq = (u16*)SM;                  // [23][264] red (A for QKV) -> q -> ctx
    u16* s_k  = (u16*)(SM + 12144);        // [23][264] k
    u16* s_v  = (u16*)(SM + 24288);        // [23][256] v
    __shared__ int sEx[23];
    __shared__ int sMiss[23];

    const int b = blockIdx.x, t = threadIdx.x;
    const int w = t >> 6, lane = t & 63;
    const int frow = lane & 15, quad = lane >> 4;
    const int r0c = frow;
    const int r1c = (16 + frow > 22) ? 22 : 16 + frow;   // clamp dup rows

    if (t < 23) sEx[t] = mask[b * 23 + t];
    __syncthreads();
    if (t == 0) {
        int any = 0;
        for (int s = 0; s < 23; ++s) any |= (sEx[s] > 0) ? 1 : 0;
        for (int s = 0; s < 23; ++s) sMiss[s] = (any && sEx[s] <= 0) ? 1 : 0;
    }
    // stage red
    for (int i = t; i < 736; i += 256) {
        const int s = i >> 5, c8 = (i & 31) * 8;
        *(uint4*)(s_rq + s * QSTR + c8) =
            *(const uint4*)(redb + ((size_t)(b * 23 + s)) * 256 + c8);
    }
    __syncthreads();

    // ---- QKV via MFMA: D[s][n] = red[s][:] . Wqkv[n][:], n in [w*192,(w+1)*192) ----
    {
        f32x4 qacc[2][12];
#pragma unroll
        for (int mt = 0; mt < 2; ++mt)
#pragma unroll
            for (int nt = 0; nt < 12; ++nt) qacc[mt][nt] = f32x4{0.f, 0.f, 0.f, 0.f};
        for (int k0 = 0; k0 < 256; k0 += 32) {
            short8 a0 = *(const short8*)(s_rq + r0c * QSTR + k0 + quad * 8);
            short8 a1 = *(const short8*)(s_rq + r1c * QSTR + k0 + quad * 8);
#pragma unroll
            for (int nt = 0; nt < 12; ++nt) {
                const int n = w * 192 + nt * 16 + frow;
                short8 bfr = *(const short8*)(Wqkvb + (size_t)n * 256 + k0 + quad * 8);
                qacc[0][nt] = __builtin_amdgcn_mfma_f32_16x16x32_bf16(a0, bfr, qacc[0][nt], 0, 0, 0);
                qacc[1][nt] = __builtin_amdgcn_mfma_f32_16x16x32_bf16(a1, bfr, qacc[1][nt], 0, 0, 0);
            }
        }
        __syncthreads();           // all A-reads of red done -> q may overlay
#pragma unroll
        for (int mt = 0; mt < 2; ++mt)
#pragma unroll
            for (int nt = 0; nt < 12; ++nt) {
                const int col = w * 192 + nt * 16 + frow;
                const int seg = col >> 8, cm = col & 255;
                const float bb = (seg == 0) ? bq[cm] : (seg == 1) ? bk[cm] : bv[cm];
#pragma unroll
                for (int reg = 0; reg < 4; ++reg) {
                    const int s = mt * 16 + quad * 4 + reg;
                    if (s < 23) {
                        const u16 hv = fbf(qacc[mt][nt][reg] + bb);
                        if (seg == 0)      s_rq[s * QSTR + cm] = hv;   // q (red dead)
                        else if (seg == 1) s_k[s * QSTR + cm] = hv;
                        else               s_v[s * 256 + cm] = hv;
                    }
                }
            }
    }
    __syncthreads();   // q,k,v visible to all

    // ---- scores + masked softmax + ctx, fused per (head,query) thread ----
    // Thread (hh,qi) reads ONLY its own q slice s_rq[qi][hh*32..], keeps probs
    // in f32 regs, computes ctx[qi][hh*32..] from s_v, and overwrites its own
    // q slice with ctx. No cross-thread hazard on s_rq => no barrier inside.
    if (t < 184) {
        const int hh = t / 23, qi = t - hh * 23;
        const u16* qrow = s_rq + qi * QSTR + hh * 32;
        float qf[32];
#pragma unroll
        for (int c8 = 0; c8 < 4; ++c8) unp8(*(const uint4*)(qrow + c8 * 8), qf + c8 * 8);
        float p[23];
        float mx = -1e30f;
#pragma unroll
        for (int j = 0; j < 23; ++j) {
            const u16* krow = s_k + j * QSTR + hh * 32;
            float sc = 0.f;
#pragma unroll
            for (int c8 = 0; c8 < 4; ++c8) {
                float kf[8]; unp8(*(const uint4*)(krow + c8 * 8), kf);
#pragma unroll
                for (int e = 0; e < 8; ++e) sc += qf[c8 * 8 + e] * kf[e];
            }
            sc *= 0.17677669529663687f;      // 1/sqrt(32)
            if (sEx[j] <= 0) sc = -1e9f;
            p[j] = sc; mx = fmaxf(mx, sc);
        }
        float sum = 0.f;
#pragma unroll
        for (int j = 0; j < 23; ++j) { p[j] = expf(p[j] - mx); sum += p[j]; }
        const float inv = 1.f / sum;

        // ctx: ct[e] = sum_j p[j] * v[j][hh*32+e], vectorized b128 v-reads
        float ct[32];
#pragma unroll
        for (int e = 0; e < 32; ++e) ct[e] = 0.f;
#pragma unroll
        for (int j = 0; j < 23; ++j) {
            const u16* vrow = s_v + j * 256 + hh * 32;
            const float pj = p[j];
#pragma unroll
            for (int c8 = 0; c8 < 4; ++c8) {
                float vf[8]; unp8(*(const uint4*)(vrow + c8 * 8), vf);
#pragma unroll
                for (int e = 0; e < 8; ++e) ct[c8 * 8 + e] += pj * vf[e];
            }
        }
        // overwrite own q slice with normalized ctx (bf16)
        u16* dst = s_rq + qi * QSTR + hh * 32;
#pragma unroll
        for (int c8 = 0; c8 < 4; ++c8) {
            float4 a = make_float4(ct[c8 * 8 + 0] * inv, ct[c8 * 8 + 1] * inv,
                                   ct[c8 * 8 + 2] * inv, ct[c8 * 8 + 3] * inv);
            float4 bq4 = make_float4(ct[c8 * 8 + 4] * inv, ct[c8 * 8 + 5] * inv,
                                     ct[c8 * 8 + 6] * inv, ct[c8 * 8 + 7] * inv);
            *(uint4*)(dst + c8 * 8) = pack8(a, bq4);
        }
    }
    __syncthreads();   // ctx (in s_rq) visible to all

    // ---- Wo via MFMA: upd[s][n] = ctx[s][:] . Wo[n][:], scatter to global ----
    {
        f32x4 wacc[2][4];
#pragma unroll
        for (int mt = 0; mt < 2; ++mt)
#pragma unroll
            for (int nt = 0; nt < 4; ++nt) wacc[mt][nt] = f32x4{0.f, 0.f, 0.f, 0.f};
        for (int k0 = 0; k0 < 256; k0 += 32) {
            short8 a0 = *(const short8*)(s_rq + r0c * QSTR + k0 + quad * 8);
            short8 a1 = *(const short8*)(s_rq + r1c * QSTR + k0 + quad * 8);
#pragma unroll
            for (int nt = 0; nt < 4; ++nt) {
                const int n = w * 64 + nt * 16 + frow;
                short8 bfr = *(const short8*)(Wob + (size_t)n * 256 + k0 + quad * 8);
                wacc[0][nt] = __builtin_amdgcn_mfma_f32_16x16x32_bf16(a0, bfr, wacc[0][nt], 0, 0, 0);
                wacc[1][nt] = __builtin_amdgcn_mfma_f32_16x16x32_bf16(a1, bfr, wacc[1][nt], 0, 0, 0);
            }
        }
#pragma unroll
        for (int mt = 0; mt < 2; ++mt)
#pragma unroll
            for (int nt = 0; nt < 4; ++nt) {
                const int col = w * 64 + nt * 16 + frow;
                const float bvv = bo[col];
#pragma unroll
                for (int reg = 0; reg < 4; ++reg) {
                    const int s = mt * 16 + quad * 4 + reg;
                    if (s < 23 && sMiss[s])
                        redb[((size_t)(b * 23 + s)) * 256 + col] =
                            fbf(wacc[mt][nt][reg] + bvv);
                }
            }
    }
}

// ---------------------------------------------------------------------------
// tail per batch element: norms + gram margin loss + pool + logits.
// LDS ~13.5 KB -> wave-limited 8 blocks/CU.
// ---------------------------------------------------------------------------
__global__ __launch_bounds__(256) void tail_kernel(
    const u16* __restrict__ redb, const u16* __restrict__ Wpb,
    const float* __restrict__ bp, float* __restrict__ out,
    float* __restrict__ lossAcc)
{
    __shared__ __align__(16) u16 s_u[23 * QSTR];
    __shared__ float sInv[23];
    __shared__ float sPool[256];
    __shared__ float sRsc[4];

    const int b = blockIdx.x, t = threadIdx.x;
    const int w = t >> 6, lane = t & 63;

    for (int i = t; i < 736; i += 256) {
        const int s = i >> 5, c8 = (i & 31) * 8;
        *(uint4*)(s_u + s * QSTR + c8) =
            *(const uint4*)(redb + ((size_t)(b * 23 + s)) * 256 + c8);
    }
    __syncthreads();

    if (t < 23) {
        float ss = 0.f;
        for (int c8 = 0; c8 < 32; ++c8) {
            float rf[8]; unp8(*(const uint4*)(s_u + t * QSTR + c8 * 8), rf);
#pragma unroll
            for (int e = 0; e < 8; ++e) ss += rf[e] * rf[e];
        }
        sInv[t] = 1.f / fmaxf(sqrtf(ss), 1e-8f);
    }
    __syncthreads();

    {
        float contrib = 0.f;
        if (t < 253) {
            int i = 0, rem = t, cnt = 22;
            while (rem >= cnt) { rem -= cnt; --cnt; ++i; }
            const int j = i + 1 + rem;
            float dp = 0.f;
            for (int c8 = 0; c8 < 32; ++c8) {
                float fa[8], fb[8];
                unp8(*(const uint4*)(s_u + i * QSTR + c8 * 8), fa);
                unp8(*(const uint4*)(s_u + j * QSTR + c8 * 8), fb);
#pragma unroll
                for (int e = 0; e < 8; ++e) dp += fa[e] * fb[e];
            }
            const float g = dp * sInv[i] * sInv[j];
            const float c = fabsf(g) - 0.1f;
            contrib = (c > 0.f) ? 2.f * c : 0.f;    // (i,j) and (j,i)
        }
#pragma unroll
        for (int m = 32; m; m >>= 1) contrib += __shfl_xor(contrib, m);
        if (lane == 0) sRsc[w] = contrib;
        __syncthreads();
        if (t == 0) atomicAdd(lossAcc, sRsc[0] + sRsc[1] + sRsc[2] + sRsc[3]);
    }

    {
        float pv = 0.f;
#pragma unroll
        for (int s = 0; s < 23; ++s) pv += bf1(s_u[s * QSTR + t]);
        sPool[t] = pv * (1.f / 23.f);
    }
    __syncthreads();
    if (t < 25) {
        float a = bp[t];
        for (int c8 = 0; c8 < 32; ++c8) {
            float wf[8]; unp8(*(const uint4*)(Wpb + (size_t)t * 256 + c8 * 8), wf);
            const float4 p0 = *(const float4*)(sPool + c8 * 8);
            const float4 p1 = *(const float4*)(sPool + c8 * 8 + 4);
            a += wf[0] * p0.x + wf[1] * p0.y + wf[2] * p0.z + wf[3] * p0.w
               + wf[4] * p1.x + wf[5] * p1.y + wf[6] * p1.z + wf[7] * p1.w;
        }
        out[1 + b * 25 + t] = a;
    }
}

__global__ void loss_finalize(const float* __restrict__ lossAcc, float* __restrict__ out)
{
    out[0] = lossAcc[0] * (1.f / 1036288.f);   // B*S*(S-1) = 2048*23*22
}

// ---------------------------------------------------------------------------
extern "C" void kernel_launch(void* const* d_in, const int* in_sizes, int n_in,
                              void* d_out, int out_size, void* d_ws, size_t ws_size,
                              hipStream_t stream)
{
    const float* cls     = (const float*)d_in[0];
    const int*   mask    = (const int*)d_in[1];
    const float* missing = (const float*)d_in[2];
    const float* W1 = (const float*)d_in[3];  const float* b1 = (const float*)d_in[4];
    const float* W2 = (const float*)d_in[5];  const float* b2 = (const float*)d_in[6];
    const float* lng = (const float*)d_in[7]; const float* lnb = (const float*)d_in[8];
    const float* Wq = (const float*)d_in[9];  const float* bq = (const float*)d_in[10];
    const float* Wk = (const float*)d_in[11]; const float* bk = (const float*)d_in[12];
    const float* Wv = (const float*)d_in[13]; const float* bv = (const float*)d_in[14];
    const float* Wo = (const float*)d_in[15]; const float* bo = (const float*)d_in[16];
    const float* Wp = (const float*)d_in[17]; const float* bp = (const float*)d_in[18];
    float* out = (float*)d_out;

    char* ws = (char*)d_ws;
    u16* h1b  = (u16*)ws;                         // [47104x384]
    u16* redb = (u16*)(ws + 36175872);            // [47104x256] red -> updated
    u16* Wb   = (u16*)(ws + 60293120);            // bf16 weights (661,760 elems)
    u16* W1b   = Wb;
    u16* W2b   = Wb + 294912;
    u16* Wqkvb = Wb + 393216;                     // q,k,v contiguous [768][256]
    u16* Wob   = Wb + 589824;
    u16* Wpb   = Wb + 655360;
    float* lossAcc = (float*)(ws + 61616640);

    hipMemsetAsync(lossAcc, 0, sizeof(float), stream);

    wconv<<<2585, 256, 0, stream>>>(W1, W2, Wq, Wk, Wv, Wo, Wp, Wb);
    // h1 = gelu(gather(cls,missing,mask) @ W1^T + b1)
    gemm1_kernel<<<dim3(3, 368), 256, 0, stream>>>(cls, mask, missing, W1b, b1, h1b);
    // h2 = gelu(h1 @ W2^T + b2) -> redb (pre-LN)
    gemm_bt<<<dim3(2, 368), 256, 0, stream>>>(h1b, W2b, b2, redb, 384, 256);
    // red = LN(h2) in-place
    ln_kernel<<<11776, 256, 0, stream>>>(redb, lng, lnb);
    // QKV + attention + Wo, scatter missing rows into redb (becomes "updated")
    attn1_kernel<<<2048, 256, 0, stream>>>(redb, mask, Wqkvb, bq, bk, bv, Wob, bo);
    // norms + gram loss + pool + logits
    tail_kernel<<<2048, 256, 0, stream>>>(redb, Wpb, bp, out, lossAcc);
    loss_finalize<<<1, 1, 0, stream>>>(lossAcc, out);
}

// Round 2
// 593.904 us; speedup vs baseline: 1.1761x; 1.1761x over previous
//
#include <hip/hip_runtime.h>

typedef unsigned short u16;
typedef unsigned int u32;
typedef __attribute__((ext_vector_type(8))) short short8;   // 8 bf16 (4 VGPRs)
typedef __attribute__((ext_vector_type(4))) float f32x4;

struct __align__(8) us4 { u16 x, y, z, w; };

__device__ __forceinline__ float bf1(u16 v){ return __uint_as_float(((u32)v) << 16); }
__device__ __forceinline__ float bflo(u32 u){ return __uint_as_float(u << 16); }
__device__ __forceinline__ float bfhi(u32 u){ return __uint_as_float(u & 0xFFFF0000u); }
__device__ __forceinline__ u16 fbf(float f){
    u32 u = __float_as_uint(f);
    return (u16)((u + 0x7FFFu + ((u >> 16) & 1u)) >> 16);   // RTNE
}
__device__ __forceinline__ float gelu_exact(float x){
    return 0.5f * x * (1.0f + erff(x * 0.70710678118654752f));
}
__device__ __forceinline__ void unp8(uint4 u, float* f){
    f[0]=bflo(u.x); f[1]=bfhi(u.x); f[2]=bflo(u.y); f[3]=bfhi(u.y);
    f[4]=bflo(u.z); f[5]=bfhi(u.z); f[6]=bflo(u.w); f[7]=bfhi(u.w);
}
__device__ __forceinline__ uint4 pack8(float4 a, float4 b){
    uint4 u;
    u.x = (u32)fbf(a.x) | ((u32)fbf(a.y) << 16);
    u.y = (u32)fbf(a.z) | ((u32)fbf(a.w) << 16);
    u.z = (u32)fbf(b.x) | ((u32)fbf(b.y) << 16);
    u.w = (u32)fbf(b.z) | ((u32)fbf(b.w) << 16);
    return u;
}

// ---------------------------------------------------------------------------
// ws layout (bytes) — total 61,616,644:
//  0          : h1b  [47104x384] bf16  (36,175,872)
//  36175872   : redb [47104x256] bf16  (24,117,248)  red -> "updated" in place
//  60293120   : Wb   bf16 weights, wconv order (661,760 elems = 1,323,520 B)
//  61616640   : lossAcc (f32)
// ---------------------------------------------------------------------------

__global__ __launch_bounds__(256) void wconv(
    const float* __restrict__ W1, const float* __restrict__ W2,
    const float* __restrict__ Wq, const float* __restrict__ Wk,
    const float* __restrict__ Wv, const float* __restrict__ Wo,
    const float* __restrict__ Wp, u16* __restrict__ dst)
{
    const int i = blockIdx.x * 256 + threadIdx.x;   // grid exactly 661760
    const float* s; int o;
    if      (i < 294912) { s = W1; o = i; }
    else if (i < 393216) { s = W2; o = i - 294912; }
    else if (i < 458752) { s = Wq; o = i - 393216; }
    else if (i < 524288) { s = Wk; o = i - 458752; }
    else if (i < 589824) { s = Wv; o = i - 524288; }
    else if (i < 655360) { s = Wo; o = i - 589824; }
    else                 { s = Wp; o = i - 655360; }
    dst[i] = fbf(s[o]);
}

// ---------------------------------------------------------------------------
// GEMM1 (fused gather): C[N,384] bf16 = gelu(sec @ W1^T + b1).
// ---------------------------------------------------------------------------
__global__ __launch_bounds__(256) void gemm1_kernel(
    const float* __restrict__ cls, const int* __restrict__ mask,
    const float* __restrict__ missing, const u16* __restrict__ W,
    const float* __restrict__ bias, u16* __restrict__ C)
{
    const int K = 768, M = 384;
    __shared__ u16 As[128 * 40];
    __shared__ u16 Bs[128 * 40];
    const int tid = threadIdx.x;
    const int w = tid >> 6, lane = tid & 63;
    const int nBase = blockIdx.y * 128, mBase = blockIdx.x * 128;
    const int wr = w >> 1, wc = w & 1;
    const int r0 = tid >> 2;
    const int co = (tid & 3) * 8;
    const int frow = lane & 15, quad = lane >> 4;

    const int rowA0 = nBase + r0, rowA1 = nBase + r0 + 64;
    const float* ap0 = (mask[rowA0] > 0) ? cls + (size_t)rowA0 * 768
                                         : missing + (size_t)(rowA0 % 23) * 768;
    const float* ap1 = (mask[rowA1] > 0) ? cls + (size_t)rowA1 * 768
                                         : missing + (size_t)(rowA1 % 23) * 768;
    const u16* bp0 = W + (size_t)(mBase + r0) * K;
    const u16* bp1 = W + (size_t)(mBase + r0 + 64) * K;

    f32x4 acc[4][4];
#pragma unroll
    for (int mt = 0; mt < 4; ++mt)
#pragma unroll
        for (int nt = 0; nt < 4; ++nt) acc[mt][nt] = f32x4{0.f, 0.f, 0.f, 0.f};

    float4 a0a = *(const float4*)(ap0 + co), a0b = *(const float4*)(ap0 + co + 4);
    float4 a1a = *(const float4*)(ap1 + co), a1b = *(const float4*)(ap1 + co + 4);
    uint4 pb0 = *(const uint4*)(bp0 + co), pb1 = *(const uint4*)(bp1 + co);

    for (int k0 = 0; k0 < K; k0 += 32) {
        __syncthreads();
        *(uint4*)(As + r0 * 40 + co) = pack8(a0a, a0b);
        *(uint4*)(As + (r0 + 64) * 40 + co) = pack8(a1a, a1b);
        *(uint4*)(Bs + r0 * 40 + co) = pb0;
        *(uint4*)(Bs + (r0 + 64) * 40 + co) = pb1;
        __syncthreads();
        if (k0 + 32 < K) {
            const int kn = k0 + 32 + co;
            a0a = *(const float4*)(ap0 + kn); a0b = *(const float4*)(ap0 + kn + 4);
            a1a = *(const float4*)(ap1 + kn); a1b = *(const float4*)(ap1 + kn + 4);
            pb0 = *(const uint4*)(bp0 + kn);  pb1 = *(const uint4*)(bp1 + kn);
        }
        short8 af[4], bfv[4];
#pragma unroll
        for (int mt = 0; mt < 4; ++mt)
            af[mt] = *(const short8*)(As + (wr * 64 + mt * 16 + frow) * 40 + quad * 8);
#pragma unroll
        for (int nt = 0; nt < 4; ++nt)
            bfv[nt] = *(const short8*)(Bs + (wc * 64 + nt * 16 + frow) * 40 + quad * 8);
#pragma unroll
        for (int mt = 0; mt < 4; ++mt)
#pragma unroll
            for (int nt = 0; nt < 4; ++nt)
                acc[mt][nt] = __builtin_amdgcn_mfma_f32_16x16x32_bf16(
                    af[mt], bfv[nt], acc[mt][nt], 0, 0, 0);
    }

#pragma unroll
    for (int nt = 0; nt < 4; ++nt) {
        const int col = mBase + wc * 64 + nt * 16 + frow;
        const float bv = bias[col];
#pragma unroll
        for (int mt = 0; mt < 4; ++mt)
#pragma unroll
            for (int reg = 0; reg < 4; ++reg) {
                const int row = nBase + wr * 64 + mt * 16 + quad * 4 + reg;
                C[(size_t)row * M + col] = fbf(gelu_exact(acc[mt][nt][reg] + bv));
            }
    }
}

// ---------------------------------------------------------------------------
// GEMM2: C[N,M] bf16 = gelu(A @ W^T + bias), bf16 inputs.
// ---------------------------------------------------------------------------
__global__ __launch_bounds__(256) void gemm_bt(
    const u16* __restrict__ A, const u16* __restrict__ W,
    const float* __restrict__ bias, u16* __restrict__ C, int K, int M)
{
    __shared__ u16 As[128 * 40];
    __shared__ u16 Bs[128 * 40];
    const int tid = threadIdx.x;
    const int w = tid >> 6, lane = tid & 63;
    const int nBase = blockIdx.y * 128, mBase = blockIdx.x * 128;
    const int wr = w >> 1, wc = w & 1;
    const int r0 = tid >> 2;
    const int co = (tid & 3) * 8;
    const int frow = lane & 15, quad = lane >> 4;

    f32x4 acc[4][4];
#pragma unroll
    for (int mt = 0; mt < 4; ++mt)
#pragma unroll
        for (int nt = 0; nt < 4; ++nt) acc[mt][nt] = f32x4{0.f, 0.f, 0.f, 0.f};

    uint4 pa0 = *(const uint4*)(A + (size_t)(nBase + r0) * K + co);
    uint4 pa1 = *(const uint4*)(A + (size_t)(nBase + r0 + 64) * K + co);
    uint4 pb0 = *(const uint4*)(W + (size_t)(mBase + r0) * K + co);
    uint4 pb1 = *(const uint4*)(W + (size_t)(mBase + r0 + 64) * K + co);

    for (int k0 = 0; k0 < K; k0 += 32) {
        __syncthreads();
        *(uint4*)(As + r0 * 40 + co) = pa0;
        *(uint4*)(As + (r0 + 64) * 40 + co) = pa1;
        *(uint4*)(Bs + r0 * 40 + co) = pb0;
        *(uint4*)(Bs + (r0 + 64) * 40 + co) = pb1;
        __syncthreads();
        if (k0 + 32 < K) {
            const int kn = k0 + 32 + co;
            pa0 = *(const uint4*)(A + (size_t)(nBase + r0) * K + kn);
            pa1 = *(const uint4*)(A + (size_t)(nBase + r0 + 64) * K + kn);
            pb0 = *(const uint4*)(W + (size_t)(mBase + r0) * K + kn);
            pb1 = *(const uint4*)(W + (size_t)(mBase + r0 + 64) * K + kn);
        }
        short8 af[4], bfv[4];
#pragma unroll
        for (int mt = 0; mt < 4; ++mt)
            af[mt] = *(const short8*)(As + (wr * 64 + mt * 16 + frow) * 40 + quad * 8);
#pragma unroll
        for (int nt = 0; nt < 4; ++nt)
            bfv[nt] = *(const short8*)(Bs + (wc * 64 + nt * 16 + frow) * 40 + quad * 8);
#pragma unroll
        for (int mt = 0; mt < 4; ++mt)
#pragma unroll
            for (int nt = 0; nt < 4; ++nt)
                acc[mt][nt] = __builtin_amdgcn_mfma_f32_16x16x32_bf16(
                    af[mt], bfv[nt], acc[mt][nt], 0, 0, 0);
    }

#pragma unroll
    for (int nt = 0; nt < 4; ++nt) {
        const int col = mBase + wc * 64 + nt * 16 + frow;
        const float bv = bias[col];
#pragma unroll
        for (int mt = 0; mt < 4; ++mt)
#pragma unroll
            for (int reg = 0; reg < 4; ++reg) {
                const int row = nBase + wr * 64 + mt * 16 + quad * 4 + reg;
                C[(size_t)row * M + col] = fbf(gelu_exact(acc[mt][nt][reg] + bv));
            }
    }
}

// ---- LayerNorm over 256, in-place bf16, 1 wave per row ----
__global__ __launch_bounds__(256) void ln_kernel(
    u16* __restrict__ X, const float* __restrict__ g, const float* __restrict__ b)
{
    const int w = threadIdx.x >> 6, lane = threadIdx.x & 63;
    const size_t row = (size_t)blockIdx.x * 4 + w;
    u16* xp = X + row * 256 + lane * 4;
    us4 uv = *(const us4*)xp;
    float x0 = bf1(uv.x), x1 = bf1(uv.y), x2 = bf1(uv.z), x3 = bf1(uv.w);
    float s = x0 + x1 + x2 + x3;
#pragma unroll
    for (int m = 32; m; m >>= 1) s += __shfl_xor(s, m);
    const float mu = s * (1.f / 256.f);
    const float d0 = x0 - mu, d1 = x1 - mu, d2 = x2 - mu, d3 = x3 - mu;
    float vs = d0 * d0 + d1 * d1 + d2 * d2 + d3 * d3;
#pragma unroll
    for (int m = 32; m; m >>= 1) vs += __shfl_xor(vs, m);
    const float rs = rsqrtf(vs * (1.f / 256.f) + 1e-5f);
    const float4 gv = *(const float4*)(g + lane * 4);
    const float4 bv = *(const float4*)(b + lane * 4);
    us4 o;
    o.x = fbf(d0 * rs * gv.x + bv.x);
    o.y = fbf(d1 * rs * gv.y + bv.y);
    o.z = fbf(d2 * rs * gv.z + bv.z);
    o.w = fbf(d3 * rs * gv.w + bv.w);
    *(us4*)xp = o;
}

// ---------------------------------------------------------------------------
// attn1 per batch element (R8): QKV (MFMA) -> scores via MFMA (K=32 = head
// dim, one K-step) -> wave-parallel softmax on D-register layout (shfl_xor
// within 16-lane groups) -> P bf16 overwrites dead k region (wave-private
// cols, no barrier) -> ctx via MFMA against transposed V (s_vT, written by
// QKV epilogue, j>=23 zero-padded) -> ctx overwrites dead q region -> Wo.
// Register peak stays in QKV phase (~130 VGPR); fused block needs ~30.
// LDS 44.9 KB -> 3 blocks/CU.
// ---------------------------------------------------------------------------
#define QSTR 264
__global__ __launch_bounds__(256) void attn1_kernel(
    u16* __restrict__ redb, const int* __restrict__ mask,
    const u16* __restrict__ Wqkvb,                       // [768][256]: q,k,v stacked
    const float* __restrict__ bq, const float* __restrict__ bk,
    const float* __restrict__ bv, const u16* __restrict__ Wob,
    const float* __restrict__ bo)
{
    __shared__ __align__(16) unsigned char SM[44768];
    u16* s_rq = (u16*)SM;                  // [23][264] red -> q -> ctx
    u16* s_k  = (u16*)(SM + 12144);        // [23][264] k -> P (bf16 probs)
    u16* s_vT = (u16*)(SM + 24288);        // [8 h][32 d][40] V^T, j>=23 zeroed
    __shared__ int sEx[23];
    __shared__ int sMiss[23];
    __shared__ float sMaskF[32];           // 0 for valid col, -1e9 for masked/pad

    const int b = blockIdx.x, t = threadIdx.x;
    const int w = t >> 6, lane = t & 63;
    const int frow = lane & 15, quad = lane >> 4;
    const int r0c = frow;
    const int r1c = (16 + frow > 22) ? 22 : 16 + frow;   // clamp dup rows

    if (t < 23) sEx[t] = mask[b * 23 + t];
    __syncthreads();
    if (t == 0) {
        int any = 0;
        for (int s = 0; s < 23; ++s) any |= (sEx[s] > 0) ? 1 : 0;
        for (int s = 0; s < 23; ++s) sMiss[s] = (any && sEx[s] <= 0) ? 1 : 0;
    }
    if (t < 32) sMaskF[t] = (t < 23 && sEx[t] > 0) ? 0.f : -1e9f;
    // zero s_vT (for the j>=23 K-pad of the ctx MFMA)
    for (int i = t; i < 1280; i += 256) ((uint4*)s_vT)[i] = make_uint4(0u, 0u, 0u, 0u);
    // stage red
    for (int i = t; i < 736; i += 256) {
        const int s = i >> 5, c8 = (i & 31) * 8;
        *(uint4*)(s_rq + s * QSTR + c8) =
            *(const uint4*)(redb + ((size_t)(b * 23 + s)) * 256 + c8);
    }
    __syncthreads();

    // ---- QKV via MFMA: D[s][n] = red[s][:] . Wqkv[n][:], n in [w*192,(w+1)*192) ----
    {
        f32x4 qacc[2][12];
#pragma unroll
        for (int mt = 0; mt < 2; ++mt)
#pragma unroll
            for (int nt = 0; nt < 12; ++nt) qacc[mt][nt] = f32x4{0.f, 0.f, 0.f, 0.f};
        for (int k0 = 0; k0 < 256; k0 += 32) {
            short8 a0 = *(const short8*)(s_rq + r0c * QSTR + k0 + quad * 8);
            short8 a1 = *(const short8*)(s_rq + r1c * QSTR + k0 + quad * 8);
#pragma unroll
            for (int nt = 0; nt < 12; ++nt) {
                const int n = w * 192 + nt * 16 + frow;
                short8 bfr = *(const short8*)(Wqkvb + (size_t)n * 256 + k0 + quad * 8);
                qacc[0][nt] = __builtin_amdgcn_mfma_f32_16x16x32_bf16(a0, bfr, qacc[0][nt], 0, 0, 0);
                qacc[1][nt] = __builtin_amdgcn_mfma_f32_16x16x32_bf16(a1, bfr, qacc[1][nt], 0, 0, 0);
            }
        }
        __syncthreads();           // all A-reads of red done -> q may overlay
#pragma unroll
        for (int mt = 0; mt < 2; ++mt)
#pragma unroll
            for (int nt = 0; nt < 12; ++nt) {
                const int col = w * 192 + nt * 16 + frow;
                const int seg = col >> 8, cm = col & 255;
                const float bb = (seg == 0) ? bq[cm] : (seg == 1) ? bk[cm] : bv[cm];
#pragma unroll
                for (int reg = 0; reg < 4; ++reg) {
                    const int s = mt * 16 + quad * 4 + reg;
                    if (s < 23) {
                        const u16 hv = fbf(qacc[mt][nt][reg] + bb);
                        if (seg == 0)      s_rq[s * QSTR + cm] = hv;        // q
                        else if (seg == 1) s_k[s * QSTR + cm] = hv;         // k
                        else               s_vT[cm * 40 + s] = hv;          // v transposed
                    }
                }
            }
    }
    __syncthreads();   // q,k,vT visible to all

    // ---- scores (MFMA) + softmax (shfl) + P write + ctx (MFMA), wave-private ----
    // Wave w owns heads 2w, 2w+1 => LDS cols [64w, 64w+64) of s_rq/s_k: its own
    // reads/writes only, so no barriers inside this block.
    {
        const float scl = 0.17677669529663687f;       // 1/sqrt(32)
        const float m0 = sMaskF[frow];                // col frow
        const float m1 = sMaskF[16 + frow];           // col 16+frow (pad -> -1e9)
        const f32x4 z4 = f32x4{0.f, 0.f, 0.f, 0.f};
#pragma unroll
        for (int hh2 = 0; hh2 < 2; ++hh2) {
            const int hb = (w * 2 + hh2) * 32;
            // scores = Q @ K^T  (A = q rows, B = k rows), one K-step (K=32)
            short8 aq0 = *(const short8*)(s_rq + r0c * QSTR + hb + quad * 8);
            short8 aq1 = *(const short8*)(s_rq + r1c * QSTR + hb + quad * 8);
            short8 bk0 = *(const short8*)(s_k + r0c * QSTR + hb + quad * 8);
            short8 bk1 = *(const short8*)(s_k + r1c * QSTR + hb + quad * 8);
            f32x4 s00 = __builtin_amdgcn_mfma_f32_16x16x32_bf16(aq0, bk0, z4, 0, 0, 0);
            f32x4 s01 = __builtin_amdgcn_mfma_f32_16x16x32_bf16(aq0, bk1, z4, 0, 0, 0);
            f32x4 s10 = __builtin_amdgcn_mfma_f32_16x16x32_bf16(aq1, bk0, z4, 0, 0, 0);
            f32x4 s11 = __builtin_amdgcn_mfma_f32_16x16x32_bf16(aq1, bk1, z4, 0, 0, 0);
            // masked softmax per row; row = 16*mt + quad*4 + reg lives in the 16
            // frow-lanes of this quad across the two nt tiles (cols frow, 16+frow).
#pragma unroll
            for (int mt = 0; mt < 2; ++mt) {
                f32x4& c0 = mt ? s10 : s00;
                f32x4& c1 = mt ? s11 : s01;
#pragma unroll
                for (int reg = 0; reg < 4; ++reg) {
                    float v0 = c0[reg] * scl + m0;
                    float v1 = c1[reg] * scl + m1;
                    float mx = fmaxf(v0, v1);
#pragma unroll
                    for (int m = 8; m; m >>= 1) mx = fmaxf(mx, __shfl_xor(mx, m));
                    float p0 = __expf(v0 - mx), p1 = __expf(v1 - mx);
                    float sm = p0 + p1;
#pragma unroll
                    for (int m = 8; m; m >>= 1) sm += __shfl_xor(sm, m);
                    const float inv = 1.f / sm;
                    c0[reg] = p0 * inv;
                    c1[reg] = p1 * inv;
                }
            }
            // write P bf16 over the dead k region (own cols). Pad cols j>=23
            // carry exp(-1e9)*inv ~= 0, which is exactly the K-pad ctx needs.
#pragma unroll
            for (int reg = 0; reg < 4; ++reg) {
                const int q0r = quad * 4 + reg;           // < 16, always valid
                s_k[q0r * QSTR + hb + frow]      = fbf(s00[reg]);
                s_k[q0r * QSTR + hb + 16 + frow] = fbf(s01[reg]);
                const int q1r = 16 + quad * 4 + reg;
                if (q1r < 23) {
                    s_k[q1r * QSTR + hb + frow]      = fbf(s10[reg]);
                    s_k[q1r * QSTR + hb + 16 + frow] = fbf(s11[reg]);
                }
            }
            // ctx = P @ V  (A = P rows from s_k, B = V^T rows from s_vT)
            short8 pa0 = *(const short8*)(s_k + r0c * QSTR + hb + quad * 8);
            short8 pa1 = *(const short8*)(s_k + r1c * QSTR + hb + quad * 8);
            short8 bv0 = *(const short8*)(s_vT + (hb + frow) * 40 + quad * 8);
            short8 bv1 = *(const short8*)(s_vT + (hb + 16 + frow) * 40 + quad * 8);
            f32x4 c00 = __builtin_amdgcn_mfma_f32_16x16x32_bf16(pa0, bv0, z4, 0, 0, 0);
            f32x4 c01 = __builtin_amdgcn_mfma_f32_16x16x32_bf16(pa0, bv1, z4, 0, 0, 0);
            f32x4 c10 = __builtin_amdgcn_mfma_f32_16x16x32_bf16(pa1, bv0, z4, 0, 0, 0);
            f32x4 c11 = __builtin_amdgcn_mfma_f32_16x16x32_bf16(pa1, bv1, z4, 0, 0, 0);
            // ctx overwrites the dead q region (own cols)
#pragma unroll
            for (int reg = 0; reg < 4; ++reg) {
                const int q0r = quad * 4 + reg;
                s_rq[q0r * QSTR + hb + frow]      = fbf(c00[reg]);
                s_rq[q0r * QSTR + hb + 16 + frow] = fbf(c01[reg]);
                const int q1r = 16 + quad * 4 + reg;
                if (q1r < 23) {
                    s_rq[q1r * QSTR + hb + frow]      = fbf(c10[reg]);
                    s_rq[q1r * QSTR + hb + 16 + frow] = fbf(c11[reg]);
                }
            }
        }
    }
    __syncthreads();   // ctx (in s_rq) visible to all

    // ---- Wo via MFMA: upd[s][n] = ctx[s][:] . Wo[n][:], scatter to global ----
    {
        f32x4 wacc[2][4];
#pragma unroll
        for (int mt = 0; mt < 2; ++mt)
#pragma unroll
            for (int nt = 0; nt < 4; ++nt) wacc[mt][nt] = f32x4{0.f, 0.f, 0.f, 0.f};
        for (int k0 = 0; k0 < 256; k0 += 32) {
            short8 a0 = *(const short8*)(s_rq + r0c * QSTR + k0 + quad * 8);
            short8 a1 = *(const short8*)(s_rq + r1c * QSTR + k0 + quad * 8);
#pragma unroll
            for (int nt = 0; nt < 4; ++nt) {
                const int n = w * 64 + nt * 16 + frow;
                short8 bfr = *(const short8*)(Wob + (size_t)n * 256 + k0 + quad * 8);
                wacc[0][nt] = __builtin_amdgcn_mfma_f32_16x16x32_bf16(a0, bfr, wacc[0][nt], 0, 0, 0);
                wacc[1][nt] = __builtin_amdgcn_mfma_f32_16x16x32_bf16(a1, bfr, wacc[1][nt], 0, 0, 0);
            }
        }
#pragma unroll
        for (int mt = 0; mt < 2; ++mt)
#pragma unroll
            for (int nt = 0; nt < 4; ++nt) {
                const int col = w * 64 + nt * 16 + frow;
                const float bvv = bo[col];
#pragma unroll
                for (int reg = 0; reg < 4; ++reg) {
                    const int s = mt * 16 + quad * 4 + reg;
                    if (s < 23 && sMiss[s])
                        redb[((size_t)(b * 23 + s)) * 256 + col] =
                            fbf(wacc[mt][nt][reg] + bvv);
                }
            }
    }
}

// ---------------------------------------------------------------------------
// tail per batch element: norms + gram margin loss + pool + logits.
// ---------------------------------------------------------------------------
__global__ __launch_bounds__(256) void tail_kernel(
    const u16* __restrict__ redb, const u16* __restrict__ Wpb,
    const float* __restrict__ bp, float* __restrict__ out,
    float* __restrict__ lossAcc)
{
    __shared__ __align__(16) u16 s_u[23 * QSTR];
    __shared__ float sInv[23];
    __shared__ float sPool[256];
    __shared__ float sRsc[4];

    const int b = blockIdx.x, t = threadIdx.x;
    const int w = t >> 6, lane = t & 63;

    for (int i = t; i < 736; i += 256) {
        const int s = i >> 5, c8 = (i & 31) * 8;
        *(uint4*)(s_u + s * QSTR + c8) =
            *(const uint4*)(redb + ((size_t)(b * 23 + s)) * 256 + c8);
    }
    __syncthreads();

    if (t < 23) {
        float ss = 0.f;
        for (int c8 = 0; c8 < 32; ++c8) {
            float rf[8]; unp8(*(const uint4*)(s_u + t * QSTR + c8 * 8), rf);
#pragma unroll
            for (int e = 0; e < 8; ++e) ss += rf[e] * rf[e];
        }
        sInv[t] = 1.f / fmaxf(sqrtf(ss), 1e-8f);
    }
    __syncthreads();

    {
        float contrib = 0.f;
        if (t < 253) {
            int i = 0, rem = t, cnt = 22;
            while (rem >= cnt) { rem -= cnt; --cnt; ++i; }
            const int j = i + 1 + rem;
            float dp = 0.f;
            for (int c8 = 0; c8 < 32; ++c8) {
                float fa[8], fb[8];
                unp8(*(const uint4*)(s_u + i * QSTR + c8 * 8), fa);
                unp8(*(const uint4*)(s_u + j * QSTR + c8 * 8), fb);
#pragma unroll
                for (int e = 0; e < 8; ++e) dp += fa[e] * fb[e];
            }
            const float g = dp * sInv[i] * sInv[j];
            const float c = fabsf(g) - 0.1f;
            contrib = (c > 0.f) ? 2.f * c : 0.f;    // (i,j) and (j,i)
        }
#pragma unroll
        for (int m = 32; m; m >>= 1) contrib += __shfl_xor(contrib, m);
        if (lane == 0) sRsc[w] = contrib;
        __syncthreads();
        if (t == 0) atomicAdd(lossAcc, sRsc[0] + sRsc[1] + sRsc[2] + sRsc[3]);
    }

    {
        float pv = 0.f;
#pragma unroll
        for (int s = 0; s < 23; ++s) pv += bf1(s_u[s * QSTR + t]);
        sPool[t] = pv * (1.f / 23.f);
    }
    __syncthreads();
    if (t < 25) {
        float a = bp[t];
        for (int c8 = 0; c8 < 32; ++c8) {
            float wf[8]; unp8(*(const uint4*)(Wpb + (size_t)t * 256 + c8 * 8), wf);
            const float4 p0 = *(const float4*)(sPool + c8 * 8);
            const float4 p1 = *(const float4*)(sPool + c8 * 8 + 4);
            a += wf[0] * p0.x + wf[1] * p0.y + wf[2] * p0.z + wf[3] * p0.w
               + wf[4] * p1.x + wf[5] * p1.y + wf[6] * p1.z + wf[7] * p1.w;
        }
        out[1 + b * 25 + t] = a;
    }
}

__global__ void loss_finalize(const float* __restrict__ lossAcc, float* __restrict__ out)
{
    out[0] = lossAcc[0] * (1.f / 1036288.f);   // B*S*(S-1) = 2048*23*22
}

// ---------------------------------------------------------------------------
extern "C" void kernel_launch(void* const* d_in, const int* in_sizes, int n_in,
                              void* d_out, int out_size, void* d_ws, size_t ws_size,
                              hipStream_t stream)
{
    const float* cls     = (const float*)d_in[0];
    const int*   mask    = (const int*)d_in[1];
    const float* missing = (const float*)d_in[2];
    const float* W1 = (const float*)d_in[3];  const float* b1 = (const float*)d_in[4];
    const float* W2 = (const float*)d_in[5];  const float* b2 = (const float*)d_in[6];
    const float* lng = (const float*)d_in[7]; const float* lnb = (const float*)d_in[8];
    const float* Wq = (const float*)d_in[9];  const float* bq = (const float*)d_in[10];
    const float* Wk = (const float*)d_in[11]; const float* bk = (const float*)d_in[12];
    const float* Wv = (const float*)d_in[13]; const float* bv = (const float*)d_in[14];
    const float* Wo = (const float*)d_in[15]; const float* bo = (const float*)d_in[16];
    const float* Wp = (const float*)d_in[17]; const float* bp = (const float*)d_in[18];
    float* out = (float*)d_out;

    char* ws = (char*)d_ws;
    u16* h1b  = (u16*)ws;                         // [47104x384]
    u16* redb = (u16*)(ws + 36175872);            // [47104x256] red -> updated
    u16* Wb   = (u16*)(ws + 60293120);            // bf16 weights (661,760 elems)
    u16* W1b   = Wb;
    u16* W2b   = Wb + 294912;
    u16* Wqkvb = Wb + 393216;                     // q,k,v contiguous [768][256]
    u16* Wob   = Wb + 589824;
    u16* Wpb   = Wb + 655360;
    float* lossAcc = (float*)(ws + 61616640);

    hipMemsetAsync(lossAcc, 0, sizeof(float), stream);

    wconv<<<2585, 256, 0, stream>>>(W1, W2, Wq, Wk, Wv, Wo, Wp, Wb);
    // h1 = gelu(gather(cls,missing,mask) @ W1^T + b1)
    gemm1_kernel<<<dim3(3, 368), 256, 0, stream>>>(cls, mask, missing, W1b, b1, h1b);
    // h2 = gelu(h1 @ W2^T + b2) -> redb (pre-LN)
    gemm_bt<<<dim3(2, 368), 256, 0, stream>>>(h1b, W2b, b2, redb, 384, 256);
    // red = LN(h2) in-place
    ln_kernel<<<11776, 256, 0, stream>>>(redb, lng, lnb);
    // QKV + attention + Wo, scatter missing rows into redb (becomes "updated")
    attn1_kernel<<<2048, 256, 0, stream>>>(redb, mask, Wqkvb, bq, bk, bv, Wob, bo);
    // norms + gram loss + pool + logits
    tail_kernel<<<2048, 256, 0, stream>>>(redb, Wpb, bp, out, lossAcc);
    loss_finalize<<<1, 1, 0, stream>>>(lossAcc, out);
}

// Round 3
// 564.012 us; speedup vs baseline: 1.2384x; 1.0530x over previous
//
#include <hip/hip_runtime.h>

typedef unsigned short u16;
typedef unsigned int u32;
typedef __attribute__((ext_vector_type(8))) short short8;   // 8 bf16 (4 VGPRs)
typedef __attribute__((ext_vector_type(4))) float f32x4;

struct __align__(8) us4 { u16 x, y, z, w; };

__device__ __forceinline__ float bf1(u16 v){ return __uint_as_float(((u32)v) << 16); }
__device__ __forceinline__ float bflo(u32 u){ return __uint_as_float(u << 16); }
__device__ __forceinline__ float bfhi(u32 u){ return __uint_as_float(u & 0xFFFF0000u); }
__device__ __forceinline__ u16 fbf(float f){
    u32 u = __float_as_uint(f);
    return (u16)((u + 0x7FFFu + ((u >> 16) & 1u)) >> 16);   // RTNE
}
__device__ __forceinline__ float gelu_exact(float x){
    return 0.5f * x * (1.0f + erff(x * 0.70710678118654752f));
}
__device__ __forceinline__ void unp8(uint4 u, float* f){
    f[0]=bflo(u.x); f[1]=bfhi(u.x); f[2]=bflo(u.y); f[3]=bfhi(u.y);
    f[4]=bflo(u.z); f[5]=bfhi(u.z); f[6]=bflo(u.w); f[7]=bfhi(u.w);
}
__device__ __forceinline__ uint4 pack8(float4 a, float4 b){
    uint4 u;
    u.x = (u32)fbf(a.x) | ((u32)fbf(a.y) << 16);
    u.y = (u32)fbf(a.z) | ((u32)fbf(a.w) << 16);
    u.z = (u32)fbf(b.x) | ((u32)fbf(b.y) << 16);
    u.w = (u32)fbf(b.z) | ((u32)fbf(b.w) << 16);
    return u;
}

// ---------------------------------------------------------------------------
// ws layout (bytes) — total 61,616,644:
//  0          : h1b  [47104x384] bf16  (36,175,872)
//  36175872   : redb [47104x256] bf16  (24,117,248)  LN output (read-only after ln)
//  60293120   : Wb   bf16 weights, wconv order (661,760 elems = 1,323,520 B)
//  61616640   : lossAcc (f32)
// ---------------------------------------------------------------------------

__global__ __launch_bounds__(256) void wconv(
    const float* __restrict__ W1, const float* __restrict__ W2,
    const float* __restrict__ Wq, const float* __restrict__ Wk,
    const float* __restrict__ Wv, const float* __restrict__ Wo,
    const float* __restrict__ Wp, u16* __restrict__ dst)
{
    const int i = blockIdx.x * 256 + threadIdx.x;   // grid exactly 661760
    const float* s; int o;
    if      (i < 294912) { s = W1; o = i; }
    else if (i < 393216) { s = W2; o = i - 294912; }
    else if (i < 458752) { s = Wq; o = i - 393216; }
    else if (i < 524288) { s = Wk; o = i - 458752; }
    else if (i < 589824) { s = Wv; o = i - 524288; }
    else if (i < 655360) { s = Wo; o = i - 589824; }
    else                 { s = Wp; o = i - 655360; }
    dst[i] = fbf(s[o]);
}

// ---------------------------------------------------------------------------
// GEMM1 (fused gather): C[N,384] bf16 = gelu(sec @ W1^T + b1).
// ---------------------------------------------------------------------------
__global__ __launch_bounds__(256) void gemm1_kernel(
    const float* __restrict__ cls, const int* __restrict__ mask,
    const float* __restrict__ missing, const u16* __restrict__ W,
    const float* __restrict__ bias, u16* __restrict__ C)
{
    const int K = 768, M = 384;
    __shared__ u16 As[128 * 40];
    __shared__ u16 Bs[128 * 40];
    const int tid = threadIdx.x;
    const int w = tid >> 6, lane = tid & 63;
    const int nBase = blockIdx.y * 128, mBase = blockIdx.x * 128;
    const int wr = w >> 1, wc = w & 1;
    const int r0 = tid >> 2;
    const int co = (tid & 3) * 8;
    const int frow = lane & 15, quad = lane >> 4;

    const int rowA0 = nBase + r0, rowA1 = nBase + r0 + 64;
    const float* ap0 = (mask[rowA0] > 0) ? cls + (size_t)rowA0 * 768
                                         : missing + (size_t)(rowA0 % 23) * 768;
    const float* ap1 = (mask[rowA1] > 0) ? cls + (size_t)rowA1 * 768
                                         : missing + (size_t)(rowA1 % 23) * 768;
    const u16* bp0 = W + (size_t)(mBase + r0) * K;
    const u16* bp1 = W + (size_t)(mBase + r0 + 64) * K;

    f32x4 acc[4][4];
#pragma unroll
    for (int mt = 0; mt < 4; ++mt)
#pragma unroll
        for (int nt = 0; nt < 4; ++nt) acc[mt][nt] = f32x4{0.f, 0.f, 0.f, 0.f};

    float4 a0a = *(const float4*)(ap0 + co), a0b = *(const float4*)(ap0 + co + 4);
    float4 a1a = *(const float4*)(ap1 + co), a1b = *(const float4*)(ap1 + co + 4);
    uint4 pb0 = *(const uint4*)(bp0 + co), pb1 = *(const uint4*)(bp1 + co);

    for (int k0 = 0; k0 < K; k0 += 32) {
        __syncthreads();
        *(uint4*)(As + r0 * 40 + co) = pack8(a0a, a0b);
        *(uint4*)(As + (r0 + 64) * 40 + co) = pack8(a1a, a1b);
        *(uint4*)(Bs + r0 * 40 + co) = pb0;
        *(uint4*)(Bs + (r0 + 64) * 40 + co) = pb1;
        __syncthreads();
        if (k0 + 32 < K) {
            const int kn = k0 + 32 + co;
            a0a = *(const float4*)(ap0 + kn); a0b = *(const float4*)(ap0 + kn + 4);
            a1a = *(const float4*)(ap1 + kn); a1b = *(const float4*)(ap1 + kn + 4);
            pb0 = *(const uint4*)(bp0 + kn);  pb1 = *(const uint4*)(bp1 + kn);
        }
        short8 af[4], bfv[4];
#pragma unroll
        for (int mt = 0; mt < 4; ++mt)
            af[mt] = *(const short8*)(As + (wr * 64 + mt * 16 + frow) * 40 + quad * 8);
#pragma unroll
        for (int nt = 0; nt < 4; ++nt)
            bfv[nt] = *(const short8*)(Bs + (wc * 64 + nt * 16 + frow) * 40 + quad * 8);
#pragma unroll
        for (int mt = 0; mt < 4; ++mt)
#pragma unroll
            for (int nt = 0; nt < 4; ++nt)
                acc[mt][nt] = __builtin_amdgcn_mfma_f32_16x16x32_bf16(
                    af[mt], bfv[nt], acc[mt][nt], 0, 0, 0);
    }

#pragma unroll
    for (int nt = 0; nt < 4; ++nt) {
        const int col = mBase + wc * 64 + nt * 16 + frow;
        const float bv = bias[col];
#pragma unroll
        for (int mt = 0; mt < 4; ++mt)
#pragma unroll
            for (int reg = 0; reg < 4; ++reg) {
                const int row = nBase + wr * 64 + mt * 16 + quad * 4 + reg;
                C[(size_t)row * M + col] = fbf(gelu_exact(acc[mt][nt][reg] + bv));
            }
    }
}

// ---------------------------------------------------------------------------
// GEMM2: C[N,M] bf16 = gelu(A @ W^T + bias), bf16 inputs.
// ---------------------------------------------------------------------------
__global__ __launch_bounds__(256) void gemm_bt(
    const u16* __restrict__ A, const u16* __restrict__ W,
    const float* __restrict__ bias, u16* __restrict__ C, int K, int M)
{
    __shared__ u16 As[128 * 40];
    __shared__ u16 Bs[128 * 40];
    const int tid = threadIdx.x;
    const int w = tid >> 6, lane = tid & 63;
    const int nBase = blockIdx.y * 128, mBase = blockIdx.x * 128;
    const int wr = w >> 1, wc = w & 1;
    const int r0 = tid >> 2;
    const int co = (tid & 3) * 8;
    const int frow = lane & 15, quad = lane >> 4;

    f32x4 acc[4][4];
#pragma unroll
    for (int mt = 0; mt < 4; ++mt)
#pragma unroll
        for (int nt = 0; nt < 4; ++nt) acc[mt][nt] = f32x4{0.f, 0.f, 0.f, 0.f};

    uint4 pa0 = *(const uint4*)(A + (size_t)(nBase + r0) * K + co);
    uint4 pa1 = *(const uint4*)(A + (size_t)(nBase + r0 + 64) * K + co);
    uint4 pb0 = *(const uint4*)(W + (size_t)(mBase + r0) * K + co);
    uint4 pb1 = *(const uint4*)(W + (size_t)(mBase + r0 + 64) * K + co);

    for (int k0 = 0; k0 < K; k0 += 32) {
        __syncthreads();
        *(uint4*)(As + r0 * 40 + co) = pa0;
        *(uint4*)(As + (r0 + 64) * 40 + co) = pa1;
        *(uint4*)(Bs + r0 * 40 + co) = pb0;
        *(uint4*)(Bs + (r0 + 64) * 40 + co) = pb1;
        __syncthreads();
        if (k0 + 32 < K) {
            const int kn = k0 + 32 + co;
            pa0 = *(const uint4*)(A + (size_t)(nBase + r0) * K + kn);
            pa1 = *(const uint4*)(A + (size_t)(nBase + r0 + 64) * K + kn);
            pb0 = *(const uint4*)(W + (size_t)(mBase + r0) * K + kn);
            pb1 = *(const uint4*)(W + (size_t)(mBase + r0 + 64) * K + kn);
        }
        short8 af[4], bfv[4];
#pragma unroll
        for (int mt = 0; mt < 4; ++mt)
            af[mt] = *(const short8*)(As + (wr * 64 + mt * 16 + frow) * 40 + quad * 8);
#pragma unroll
        for (int nt = 0; nt < 4; ++nt)
            bfv[nt] = *(const short8*)(Bs + (wc * 64 + nt * 16 + frow) * 40 + quad * 8);
#pragma unroll
        for (int mt = 0; mt < 4; ++mt)
#pragma unroll
            for (int nt = 0; nt < 4; ++nt)
                acc[mt][nt] = __builtin_amdgcn_mfma_f32_16x16x32_bf16(
                    af[mt], bfv[nt], acc[mt][nt], 0, 0, 0);
    }

#pragma unroll
    for (int nt = 0; nt < 4; ++nt) {
        const int col = mBase + wc * 64 + nt * 16 + frow;
        const float bv = bias[col];
#pragma unroll
        for (int mt = 0; mt < 4; ++mt)
#pragma unroll
            for (int reg = 0; reg < 4; ++reg) {
                const int row = nBase + wr * 64 + mt * 16 + quad * 4 + reg;
                C[(size_t)row * M + col] = fbf(gelu_exact(acc[mt][nt][reg] + bv));
            }
    }
}

// ---- LayerNorm over 256, in-place bf16, 1 wave per row ----
__global__ __launch_bounds__(256) void ln_kernel(
    u16* __restrict__ X, const float* __restrict__ g, const float* __restrict__ b)
{
    const int w = threadIdx.x >> 6, lane = threadIdx.x & 63;
    const size_t row = (size_t)blockIdx.x * 4 + w;
    u16* xp = X + row * 256 + lane * 4;
    us4 uv = *(const us4*)xp;
    float x0 = bf1(uv.x), x1 = bf1(uv.y), x2 = bf1(uv.z), x3 = bf1(uv.w);
    float s = x0 + x1 + x2 + x3;
#pragma unroll
    for (int m = 32; m; m >>= 1) s += __shfl_xor(s, m);
    const float mu = s * (1.f / 256.f);
    const float d0 = x0 - mu, d1 = x1 - mu, d2 = x2 - mu, d3 = x3 - mu;
    float vs = d0 * d0 + d1 * d1 + d2 * d2 + d3 * d3;
#pragma unroll
    for (int m = 32; m; m >>= 1) vs += __shfl_xor(vs, m);
    const float rs = rsqrtf(vs * (1.f / 256.f) + 1e-5f);
    const float4 gv = *(const float4*)(g + lane * 4);
    const float4 bv = *(const float4*)(b + lane * 4);
    us4 o;
    o.x = fbf(d0 * rs * gv.x + bv.x);
    o.y = fbf(d1 * rs * gv.y + bv.y);
    o.z = fbf(d2 * rs * gv.z + bv.z);
    o.w = fbf(d3 * rs * gv.w + bv.w);
    *(us4*)xp = o;
}

// ---------------------------------------------------------------------------
// attn_tail (R9): per batch element, fully fused attention + tail.
//   stage red -> QKV (wave-private head mapping: wave w owns q/k/v cols
//   [64w,64w+64)) -> scores/softmax/P/ctx via MFMA, all wave-private (no
//   barrier) -> Wo -> `updated` assembled in LDS (wacc for missing rows,
//   redb re-read for existing) -> norms + gram loss + pool + logits.
// No global scatter, no tail kernel, no tail restage.
// LDS exactly 40960 B => 4 blocks/CU. Tail scratch aliases dead s_vT.
// ---------------------------------------------------------------------------
#define QSTR 264
__global__ __launch_bounds__(256) void attn_tail_kernel(
    const u16* __restrict__ redb, const int* __restrict__ mask,
    const u16* __restrict__ Wqkvb,                       // [768][256]: q,k,v stacked
    const float* __restrict__ bq, const float* __restrict__ bk,
    const float* __restrict__ bv, const u16* __restrict__ Wob,
    const float* __restrict__ bo, const u16* __restrict__ Wpb,
    const float* __restrict__ bp, float* __restrict__ out,
    float* __restrict__ lossAcc)
{
    __shared__ __align__(16) unsigned char SM[40960];
    u16* s_rq = (u16*)SM;                  // [23][264] red -> q -> ctx
    u16* s_k  = (u16*)(SM + 12144);        // [23][264] k -> P -> updated
    u16* s_vT = (u16*)(SM + 24288);        // [256][32] V^T (stride 32), j>=23 zero
    int* sEx   = (int*)(SM + 40672);       // [23]
    int* sMiss = (int*)(SM + 40764);       // [23]
    // tail scratch aliases the dead s_vT region:
    float* sInv  = (float*)(SM + 24288);   // [23]
    float* sPool = (float*)(SM + 24384);   // [256]
    float* sRsc  = (float*)(SM + 25472);   // [4]

    const int b = blockIdx.x, t = threadIdx.x;
    const int w = t >> 6, lane = t & 63;
    const int frow = lane & 15, quad = lane >> 4;
    const int r0c = frow;
    const int r1c = (16 + frow > 22) ? 22 : 16 + frow;   // clamp dup rows

    // mask -> sEx/sMiss via wave-0 ballot (no serial loop, no extra barrier:
    // consumers read after later barriers).
    {
        const int myEx = (t < 23) ? mask[b * 23 + t] : 0;
        if (t < 23) sEx[t] = myEx;
        if (t < 64) {
            const unsigned long long ball = __ballot((t < 23) && (myEx > 0));
            if (t < 23) sMiss[t] = (ball != 0ull && myEx <= 0) ? 1 : 0;
        }
    }
    // zero s_vT (j>=23 K-pad for ctx MFMA): 16384 B = 1024 uint4
    for (int i = t; i < 1024; i += 256) ((uint4*)s_vT)[i] = make_uint4(0u, 0u, 0u, 0u);
    // stage red
    for (int i = t; i < 736; i += 256) {
        const int s = i >> 5, c8 = (i & 31) * 8;
        *(uint4*)(s_rq + s * QSTR + c8) =
            *(const uint4*)(redb + ((size_t)(b * 23 + s)) * 256 + c8);
    }
    __syncthreads();

    // ---- QKV via MFMA, wave-private head mapping ----
    // nt 0-3: q cols 64w+..  | nt 4-7: k cols | nt 8-11: v cols (transposed store)
    {
        f32x4 qacc[2][12];
#pragma unroll
        for (int mt = 0; mt < 2; ++mt)
#pragma unroll
            for (int nt = 0; nt < 12; ++nt) qacc[mt][nt] = f32x4{0.f, 0.f, 0.f, 0.f};
        for (int k0 = 0; k0 < 256; k0 += 32) {
            short8 a0 = *(const short8*)(s_rq + r0c * QSTR + k0 + quad * 8);
            short8 a1 = *(const short8*)(s_rq + r1c * QSTR + k0 + quad * 8);
#pragma unroll
            for (int nt = 0; nt < 12; ++nt) {
                const int n = (nt >> 2) * 256 + w * 64 + (nt & 3) * 16 + frow;
                short8 bfr = *(const short8*)(Wqkvb + (size_t)n * 256 + k0 + quad * 8);
                qacc[0][nt] = __builtin_amdgcn_mfma_f32_16x16x32_bf16(a0, bfr, qacc[0][nt], 0, 0, 0);
                qacc[1][nt] = __builtin_amdgcn_mfma_f32_16x16x32_bf16(a1, bfr, qacc[1][nt], 0, 0, 0);
            }
        }
        __syncthreads();           // all A-reads of red done -> q may overlay
#pragma unroll
        for (int nt = 0; nt < 12; ++nt) {
            const int seg = nt >> 2;                       // compile-time per nt
            const int cm = w * 64 + (nt & 3) * 16 + frow;  // own col range
            const float bb = (seg == 0) ? bq[cm] : (seg == 1) ? bk[cm] : bv[cm];
#pragma unroll
            for (int mt = 0; mt < 2; ++mt)
#pragma unroll
                for (int reg = 0; reg < 4; ++reg) {
                    const int s = mt * 16 + quad * 4 + reg;
                    if (s < 23) {
                        const u16 hv = fbf(qacc[mt][nt][reg] + bb);
                        if (seg == 0)      s_rq[s * QSTR + cm] = hv;   // q
                        else if (seg == 1) s_k[s * QSTR + cm] = hv;    // k
                        else               s_vT[cm * 32 + s] = hv;     // v^T
                    }
                }
        }
    }
    // NO barrier: wave w's scores/ctx read only the q/k/vT cols it just wrote.

    // ---- scores (MFMA) + softmax (shfl) + P write + ctx (MFMA), wave-private ----
    {
        const float scl = 0.17677669529663687f;       // 1/sqrt(32)
        const float m0 = (sEx[frow] > 0) ? 0.f : -1e9f;                 // col frow
        const float m1 = (16 + frow < 23 && sEx[16 + frow] > 0) ? 0.f : -1e9f;
        const f32x4 z4 = f32x4{0.f, 0.f, 0.f, 0.f};
#pragma unroll
        for (int hh2 = 0; hh2 < 2; ++hh2) {
            const int hb = w * 64 + hh2 * 32;
            // scores = Q @ K^T  (A = q rows, B = k rows), one K-step (K=32)
            short8 aq0 = *(const short8*)(s_rq + r0c * QSTR + hb + quad * 8);
            short8 aq1 = *(const short8*)(s_rq + r1c * QSTR + hb + quad * 8);
            short8 bk0 = *(const short8*)(s_k + r0c * QSTR + hb + quad * 8);
            short8 bk1 = *(const short8*)(s_k + r1c * QSTR + hb + quad * 8);
            f32x4 s00 = __builtin_amdgcn_mfma_f32_16x16x32_bf16(aq0, bk0, z4, 0, 0, 0);
            f32x4 s01 = __builtin_amdgcn_mfma_f32_16x16x32_bf16(aq0, bk1, z4, 0, 0, 0);
            f32x4 s10 = __builtin_amdgcn_mfma_f32_16x16x32_bf16(aq1, bk0, z4, 0, 0, 0);
            f32x4 s11 = __builtin_amdgcn_mfma_f32_16x16x32_bf16(aq1, bk1, z4, 0, 0, 0);
            // masked softmax per row (row in 16-lane frow group; cols frow, 16+frow)
#pragma unroll
            for (int mt = 0; mt < 2; ++mt) {
                f32x4& c0 = mt ? s10 : s00;
                f32x4& c1 = mt ? s11 : s01;
#pragma unroll
                for (int reg = 0; reg < 4; ++reg) {
                    float v0 = c0[reg] * scl + m0;
                    float v1 = c1[reg] * scl + m1;
                    float mx = fmaxf(v0, v1);
#pragma unroll
                    for (int m = 8; m; m >>= 1) mx = fmaxf(mx, __shfl_xor(mx, m));
                    float p0 = __expf(v0 - mx), p1 = __expf(v1 - mx);
                    float sm = p0 + p1;
#pragma unroll
                    for (int m = 8; m; m >>= 1) sm += __shfl_xor(sm, m);
                    const float inv = 1.f / sm;
                    c0[reg] = p0 * inv;
                    c1[reg] = p1 * inv;
                }
            }
            // write P bf16 over the dead k region (own cols); pad cols ~0.
#pragma unroll
            for (int reg = 0; reg < 4; ++reg) {
                const int q0r = quad * 4 + reg;           // < 16, always valid
                s_k[q0r * QSTR + hb + frow]      = fbf(s00[reg]);
                s_k[q0r * QSTR + hb + 16 + frow] = fbf(s01[reg]);
                const int q1r = 16 + quad * 4 + reg;
                if (q1r < 23) {
                    s_k[q1r * QSTR + hb + frow]      = fbf(s10[reg]);
                    s_k[q1r * QSTR + hb + 16 + frow] = fbf(s11[reg]);
                }
            }
            // ctx = P @ V  (A = P rows from s_k, B = V^T rows from s_vT)
            short8 pa0 = *(const short8*)(s_k + r0c * QSTR + hb + quad * 8);
            short8 pa1 = *(const short8*)(s_k + r1c * QSTR + hb + quad * 8);
            short8 bv0 = *(const short8*)(s_vT + (hb + frow) * 32 + quad * 8);
            short8 bv1 = *(const short8*)(s_vT + (hb + 16 + frow) * 32 + quad * 8);
            f32x4 c00 = __builtin_amdgcn_mfma_f32_16x16x32_bf16(pa0, bv0, z4, 0, 0, 0);
            f32x4 c01 = __builtin_amdgcn_mfma_f32_16x16x32_bf16(pa0, bv1, z4, 0, 0, 0);
            f32x4 c10 = __builtin_amdgcn_mfma_f32_16x16x32_bf16(pa1, bv0, z4, 0, 0, 0);
            f32x4 c11 = __builtin_amdgcn_mfma_f32_16x16x32_bf16(pa1, bv1, z4, 0, 0, 0);
            // ctx overwrites the dead q region (own cols)
#pragma unroll
            for (int reg = 0; reg < 4; ++reg) {
                const int q0r = quad * 4 + reg;
                s_rq[q0r * QSTR + hb + frow]      = fbf(c00[reg]);
                s_rq[q0r * QSTR + hb + 16 + frow] = fbf(c01[reg]);
                const int q1r = 16 + quad * 4 + reg;
                if (q1r < 23) {
                    s_rq[q1r * QSTR + hb + frow]      = fbf(c10[reg]);
                    s_rq[q1r * QSTR + hb + 16 + frow] = fbf(c11[reg]);
                }
            }
        }
    }
    __syncthreads();   // ctx (in s_rq) visible to all

    // ---- Wo via MFMA + assemble `updated` in s_k (no global scatter) ----
    {
        f32x4 wacc[2][4];
#pragma unroll
        for (int mt = 0; mt < 2; ++mt)
#pragma unroll
            for (int nt = 0; nt < 4; ++nt) wacc[mt][nt] = f32x4{0.f, 0.f, 0.f, 0.f};
        for (int k0 = 0; k0 < 256; k0 += 32) {
            short8 a0 = *(const short8*)(s_rq + r0c * QSTR + k0 + quad * 8);
            short8 a1 = *(const short8*)(s_rq + r1c * QSTR + k0 + quad * 8);
#pragma unroll
            for (int nt = 0; nt < 4; ++nt) {
                const int n = w * 64 + nt * 16 + frow;
                short8 bfr = *(const short8*)(Wob + (size_t)n * 256 + k0 + quad * 8);
                wacc[0][nt] = __builtin_amdgcn_mfma_f32_16x16x32_bf16(a0, bfr, wacc[0][nt], 0, 0, 0);
                wacc[1][nt] = __builtin_amdgcn_mfma_f32_16x16x32_bf16(a1, bfr, wacc[1][nt], 0, 0, 0);
            }
        }
        // existing rows: re-stage red from redb (L2-hot, unmodified)
        for (int i = t; i < 736; i += 256) {
            const int s = i >> 5;
            if (!sMiss[s]) {
                const int c8 = (i & 31) * 8;
                *(uint4*)(s_k + s * QSTR + c8) =
                    *(const uint4*)(redb + ((size_t)(b * 23 + s)) * 256 + c8);
            }
        }
        // missing rows: mha_out = wacc + bo (own cols; disjoint from stage rows)
#pragma unroll
        for (int nt = 0; nt < 4; ++nt) {
            const int col = w * 64 + nt * 16 + frow;
            const float bvv = bo[col];
#pragma unroll
            for (int mt = 0; mt < 2; ++mt)
#pragma unroll
                for (int reg = 0; reg < 4; ++reg) {
                    const int s = mt * 16 + quad * 4 + reg;
                    if (s < 23 && sMiss[s])
                        s_k[s * QSTR + col] = fbf(wacc[mt][nt][reg] + bvv);
                }
        }
    }
    __syncthreads();   // s_k = updated [23][256]

    // ---- tail: row norms ----
    if (t < 23) {
        float ss = 0.f;
        for (int c8 = 0; c8 < 32; ++c8) {
            float rf[8]; unp8(*(const uint4*)(s_k + t * QSTR + c8 * 8), rf);
#pragma unroll
            for (int e = 0; e < 8; ++e) ss += rf[e] * rf[e];
        }
        sInv[t] = 1.f / fmaxf(sqrtf(ss), 1e-8f);
    }
    __syncthreads();

    // ---- gram margin loss + pool (one barrier for both) ----
    {
        float contrib = 0.f;
        if (t < 253) {
            int i = 0, rem = t, cnt = 22;
            while (rem >= cnt) { rem -= cnt; --cnt; ++i; }
            const int j = i + 1 + rem;
            float dp = 0.f;
            for (int c8 = 0; c8 < 32; ++c8) {
                float fa[8], fb[8];
                unp8(*(const uint4*)(s_k + i * QSTR + c8 * 8), fa);
                unp8(*(const uint4*)(s_k + j * QSTR + c8 * 8), fb);
#pragma unroll
                for (int e = 0; e < 8; ++e) dp += fa[e] * fb[e];
            }
            const float g = dp * sInv[i] * sInv[j];
            const float c = fabsf(g) - 0.1f;
            contrib = (c > 0.f) ? 2.f * c : 0.f;    // (i,j) and (j,i)
        }
#pragma unroll
        for (int m = 32; m; m >>= 1) contrib += __shfl_xor(contrib, m);
        if (lane == 0) sRsc[w] = contrib;

        float pv = 0.f;
#pragma unroll
        for (int s = 0; s < 23; ++s) pv += bf1(s_k[s * QSTR + t]);
        sPool[t] = pv * (1.f / 23.f);
    }
    __syncthreads();

    if (t == 0) atomicAdd(lossAcc, sRsc[0] + sRsc[1] + sRsc[2] + sRsc[3]);
    if (t < 25) {
        float a = bp[t];
        for (int c8 = 0; c8 < 32; ++c8) {
            float wf[8]; unp8(*(const uint4*)(Wpb + (size_t)t * 256 + c8 * 8), wf);
            const float4 p0 = *(const float4*)(sPool + c8 * 8);
            const float4 p1 = *(const float4*)(sPool + c8 * 8 + 4);
            a += wf[0] * p0.x + wf[1] * p0.y + wf[2] * p0.z + wf[3] * p0.w
               + wf[4] * p1.x + wf[5] * p1.y + wf[6] * p1.z + wf[7] * p1.w;
        }
        out[1 + b * 25 + t] = a;
    }
}

__global__ void loss_finalize(const float* __restrict__ lossAcc, float* __restrict__ out)
{
    out[0] = lossAcc[0] * (1.f / 1036288.f);   // B*S*(S-1) = 2048*23*22
}

// ---------------------------------------------------------------------------
extern "C" void kernel_launch(void* const* d_in, const int* in_sizes, int n_in,
                              void* d_out, int out_size, void* d_ws, size_t ws_size,
                              hipStream_t stream)
{
    const float* cls     = (const float*)d_in[0];
    const int*   mask    = (const int*)d_in[1];
    const float* missing = (const float*)d_in[2];
    const float* W1 = (const float*)d_in[3];  const float* b1 = (const float*)d_in[4];
    const float* W2 = (const float*)d_in[5];  const float* b2 = (const float*)d_in[6];
    const float* lng = (const float*)d_in[7]; const float* lnb = (const float*)d_in[8];
    const float* Wq = (const float*)d_in[9];  const float* bq = (const float*)d_in[10];
    const float* Wk = (const float*)d_in[11]; const float* bk = (const float*)d_in[12];
    const float* Wv = (const float*)d_in[13]; const float* bv = (const float*)d_in[14];
    const float* Wo = (const float*)d_in[15]; const float* bo = (const float*)d_in[16];
    const float* Wp = (const float*)d_in[17]; const float* bp = (const float*)d_in[18];
    float* out = (float*)d_out;

    char* ws = (char*)d_ws;
    u16* h1b  = (u16*)ws;                         // [47104x384]
    u16* redb = (u16*)(ws + 36175872);            // [47104x256] LN output
    u16* Wb   = (u16*)(ws + 60293120);            // bf16 weights (661,760 elems)
    u16* W1b   = Wb;
    u16* W2b   = Wb + 294912;
    u16* Wqkvb = Wb + 393216;                     // q,k,v contiguous [768][256]
    u16* Wob   = Wb + 589824;
    u16* Wpb   = Wb + 655360;
    float* lossAcc = (float*)(ws + 61616640);

    hipMemsetAsync(lossAcc, 0, sizeof(float), stream);

    wconv<<<2585, 256, 0, stream>>>(W1, W2, Wq, Wk, Wv, Wo, Wp, Wb);
    // h1 = gelu(gather(cls,missing,mask) @ W1^T + b1)
    gemm1_kernel<<<dim3(3, 368), 256, 0, stream>>>(cls, mask, missing, W1b, b1, h1b);
    // h2 = gelu(h1 @ W2^T + b2) -> redb (pre-LN)
    gemm_bt<<<dim3(2, 368), 256, 0, stream>>>(h1b, W2b, b2, redb, 384, 256);
    // red = LN(h2) in-place
    ln_kernel<<<11776, 256, 0, stream>>>(redb, lng, lnb);
    // fused: QKV + attention + Wo + updated + gram loss + pool + logits
    attn_tail_kernel<<<2048, 256, 0, stream>>>(redb, mask, Wqkvb, bq, bk, bv,
                                               Wob, bo, Wpb, bp, out, lossAcc);
    loss_finalize<<<1, 1, 0, stream>>>(lossAcc, out);
}

// Round 4
// 550.496 us; speedup vs baseline: 1.2689x; 1.0246x over previous
//
#include <hip/hip_runtime.h>

typedef unsigned short u16;
typedef unsigned int u32;
typedef __attribute__((ext_vector_type(8))) short short8;   // 8 bf16 (4 VGPRs)
typedef __attribute__((ext_vector_type(4))) float f32x4;

struct __align__(8) us4 { u16 x, y, z, w; };

__device__ __forceinline__ float bf1(u16 v){ return __uint_as_float(((u32)v) << 16); }
__device__ __forceinline__ float bflo(u32 u){ return __uint_as_float(u << 16); }
__device__ __forceinline__ float bfhi(u32 u){ return __uint_as_float(u & 0xFFFF0000u); }
__device__ __forceinline__ u16 fbf(float f){
    u32 u = __float_as_uint(f);
    return (u16)((u + 0x7FFFu + ((u >> 16) & 1u)) >> 16);   // RTNE
}
__device__ __forceinline__ float gelu_exact(float x){
    return 0.5f * x * (1.0f + erff(x * 0.70710678118654752f));
}
__device__ __forceinline__ void unp8(uint4 u, float* f){
    f[0]=bflo(u.x); f[1]=bfhi(u.x); f[2]=bflo(u.y); f[3]=bfhi(u.y);
    f[4]=bflo(u.z); f[5]=bfhi(u.z); f[6]=bflo(u.w); f[7]=bfhi(u.w);
}
__device__ __forceinline__ uint4 pack8(float4 a, float4 b){
    uint4 u;
    u.x = (u32)fbf(a.x) | ((u32)fbf(a.y) << 16);
    u.y = (u32)fbf(a.z) | ((u32)fbf(a.w) << 16);
    u.z = (u32)fbf(b.x) | ((u32)fbf(b.y) << 16);
    u.w = (u32)fbf(b.z) | ((u32)fbf(b.w) << 16);
    return u;
}

#define MFMA16(a, b, c) __builtin_amdgcn_mfma_f32_16x16x32_bf16(a, b, c, 0, 0, 0)
#define QSTR 264

// ---------------------------------------------------------------------------
// ws layout (bytes) — total 61,616,644:
//  0          : h1b  [47104x384] bf16  (36,175,872)
//  36175872   : redb [47104x256] bf16  (24,117,248)  h2 = gelu(...) PRE-LN
//  60293120   : Wb   bf16 weights, wconv order (661,760 elems = 1,323,520 B)
//  61616640   : lossAcc (f32)
// ---------------------------------------------------------------------------

__global__ __launch_bounds__(256) void wconv(
    const float* __restrict__ W1, const float* __restrict__ W2,
    const float* __restrict__ Wq, const float* __restrict__ Wk,
    const float* __restrict__ Wv, const float* __restrict__ Wo,
    const float* __restrict__ Wp, u16* __restrict__ dst)
{
    const int i = blockIdx.x * 256 + threadIdx.x;   // grid exactly 661760
    const float* s; int o;
    if      (i < 294912) { s = W1; o = i; }
    else if (i < 393216) { s = W2; o = i - 294912; }
    else if (i < 458752) { s = Wq; o = i - 393216; }
    else if (i < 524288) { s = Wk; o = i - 458752; }
    else if (i < 589824) { s = Wv; o = i - 524288; }
    else if (i < 655360) { s = Wo; o = i - 589824; }
    else                 { s = Wp; o = i - 655360; }
    dst[i] = fbf(s[o]);
}

// ---------------------------------------------------------------------------
// GEMM1 (fused gather): C[N,384] bf16 = gelu(sec @ W1^T + b1).
// ---------------------------------------------------------------------------
__global__ __launch_bounds__(256) void gemm1_kernel(
    const float* __restrict__ cls, const int* __restrict__ mask,
    const float* __restrict__ missing, const u16* __restrict__ W,
    const float* __restrict__ bias, u16* __restrict__ C)
{
    const int K = 768, M = 384;
    __shared__ u16 As[128 * 40];
    __shared__ u16 Bs[128 * 40];
    const int tid = threadIdx.x;
    const int w = tid >> 6, lane = tid & 63;
    const int nBase = blockIdx.y * 128, mBase = blockIdx.x * 128;
    const int wr = w >> 1, wc = w & 1;
    const int r0 = tid >> 2;
    const int co = (tid & 3) * 8;
    const int frow = lane & 15, quad = lane >> 4;

    const int rowA0 = nBase + r0, rowA1 = nBase + r0 + 64;
    const float* ap0 = (mask[rowA0] > 0) ? cls + (size_t)rowA0 * 768
                                         : missing + (size_t)(rowA0 % 23) * 768;
    const float* ap1 = (mask[rowA1] > 0) ? cls + (size_t)rowA1 * 768
                                         : missing + (size_t)(rowA1 % 23) * 768;
    const u16* bp0 = W + (size_t)(mBase + r0) * K;
    const u16* bp1 = W + (size_t)(mBase + r0 + 64) * K;

    f32x4 acc[4][4];
#pragma unroll
    for (int mt = 0; mt < 4; ++mt)
#pragma unroll
        for (int nt = 0; nt < 4; ++nt) acc[mt][nt] = f32x4{0.f, 0.f, 0.f, 0.f};

    float4 a0a = *(const float4*)(ap0 + co), a0b = *(const float4*)(ap0 + co + 4);
    float4 a1a = *(const float4*)(ap1 + co), a1b = *(const float4*)(ap1 + co + 4);
    uint4 pb0 = *(const uint4*)(bp0 + co), pb1 = *(const uint4*)(bp1 + co);

    for (int k0 = 0; k0 < K; k0 += 32) {
        __syncthreads();
        *(uint4*)(As + r0 * 40 + co) = pack8(a0a, a0b);
        *(uint4*)(As + (r0 + 64) * 40 + co) = pack8(a1a, a1b);
        *(uint4*)(Bs + r0 * 40 + co) = pb0;
        *(uint4*)(Bs + (r0 + 64) * 40 + co) = pb1;
        __syncthreads();
        if (k0 + 32 < K) {
            const int kn = k0 + 32 + co;
            a0a = *(const float4*)(ap0 + kn); a0b = *(const float4*)(ap0 + kn + 4);
            a1a = *(const float4*)(ap1 + kn); a1b = *(const float4*)(ap1 + kn + 4);
            pb0 = *(const uint4*)(bp0 + kn);  pb1 = *(const uint4*)(bp1 + kn);
        }
        short8 af[4], bfv[4];
#pragma unroll
        for (int mt = 0; mt < 4; ++mt)
            af[mt] = *(const short8*)(As + (wr * 64 + mt * 16 + frow) * 40 + quad * 8);
#pragma unroll
        for (int nt = 0; nt < 4; ++nt)
            bfv[nt] = *(const short8*)(Bs + (wc * 64 + nt * 16 + frow) * 40 + quad * 8);
#pragma unroll
        for (int mt = 0; mt < 4; ++mt)
#pragma unroll
            for (int nt = 0; nt < 4; ++nt)
                acc[mt][nt] = MFMA16(af[mt], bfv[nt], acc[mt][nt]);
    }

#pragma unroll
    for (int nt = 0; nt < 4; ++nt) {
        const int col = mBase + wc * 64 + nt * 16 + frow;
        const float bv = bias[col];
#pragma unroll
        for (int mt = 0; mt < 4; ++mt)
#pragma unroll
            for (int reg = 0; reg < 4; ++reg) {
                const int row = nBase + wr * 64 + mt * 16 + quad * 4 + reg;
                C[(size_t)row * M + col] = fbf(gelu_exact(acc[mt][nt][reg] + bv));
            }
    }
}

// ---------------------------------------------------------------------------
// GEMM2: C[N,M] bf16 = gelu(A @ W^T + bias), bf16 inputs.
// ---------------------------------------------------------------------------
__global__ __launch_bounds__(256) void gemm_bt(
    const u16* __restrict__ A, const u16* __restrict__ W,
    const float* __restrict__ bias, u16* __restrict__ C, int K, int M)
{
    __shared__ u16 As[128 * 40];
    __shared__ u16 Bs[128 * 40];
    const int tid = threadIdx.x;
    const int w = tid >> 6, lane = tid & 63;
    const int nBase = blockIdx.y * 128, mBase = blockIdx.x * 128;
    const int wr = w >> 1, wc = w & 1;
    const int r0 = tid >> 2;
    const int co = (tid & 3) * 8;
    const int frow = lane & 15, quad = lane >> 4;

    f32x4 acc[4][4];
#pragma unroll
    for (int mt = 0; mt < 4; ++mt)
#pragma unroll
        for (int nt = 0; nt < 4; ++nt) acc[mt][nt] = f32x4{0.f, 0.f, 0.f, 0.f};

    uint4 pa0 = *(const uint4*)(A + (size_t)(nBase + r0) * K + co);
    uint4 pa1 = *(const uint4*)(A + (size_t)(nBase + r0 + 64) * K + co);
    uint4 pb0 = *(const uint4*)(W + (size_t)(mBase + r0) * K + co);
    uint4 pb1 = *(const uint4*)(W + (size_t)(mBase + r0 + 64) * K + co);

    for (int k0 = 0; k0 < K; k0 += 32) {
        __syncthreads();
        *(uint4*)(As + r0 * 40 + co) = pa0;
        *(uint4*)(As + (r0 + 64) * 40 + co) = pa1;
        *(uint4*)(Bs + r0 * 40 + co) = pb0;
        *(uint4*)(Bs + (r0 + 64) * 40 + co) = pb1;
        __syncthreads();
        if (k0 + 32 < K) {
            const int kn = k0 + 32 + co;
            pa0 = *(const uint4*)(A + (size_t)(nBase + r0) * K + kn);
            pa1 = *(const uint4*)(A + (size_t)(nBase + r0 + 64) * K + kn);
            pb0 = *(const uint4*)(W + (size_t)(mBase + r0) * K + kn);
            pb1 = *(const uint4*)(W + (size_t)(mBase + r0 + 64) * K + kn);
        }
        short8 af[4], bfv[4];
#pragma unroll
        for (int mt = 0; mt < 4; ++mt)
            af[mt] = *(const short8*)(As + (wr * 64 + mt * 16 + frow) * 40 + quad * 8);
#pragma unroll
        for (int nt = 0; nt < 4; ++nt)
            bfv[nt] = *(const short8*)(Bs + (wc * 64 + nt * 16 + frow) * 40 + quad * 8);
#pragma unroll
        for (int mt = 0; mt < 4; ++mt)
#pragma unroll
            for (int nt = 0; nt < 4; ++nt)
                acc[mt][nt] = MFMA16(af[mt], bfv[nt], acc[mt][nt]);
    }

#pragma unroll
    for (int nt = 0; nt < 4; ++nt) {
        const int col = mBase + wc * 64 + nt * 16 + frow;
        const float bv = bias[col];
#pragma unroll
        for (int mt = 0; mt < 4; ++mt)
#pragma unroll
            for (int reg = 0; reg < 4; ++reg) {
                const int row = nBase + wr * 64 + mt * 16 + quad * 4 + reg;
                C[(size_t)row * M + col] = fbf(gelu_exact(acc[mt][nt][reg] + bv));
            }
    }
}

// ---- LN over a [23][QSTR] LDS tile, in place. 8 threads/row (t>>3 = row),
// shfl_xor over the 8-lane group. Threads t>=184 idle (whole groups). ----
__device__ __forceinline__ void ln_rows_inplace(
    u16* base, int t, const float* __restrict__ lng, const float* __restrict__ lnb)
{
    const int r = t >> 3, sub = t & 7;
    if (r >= 23) return;
    u16* rp = base + r * QSTR + sub * 32;
    float x[32];
    unp8(((const uint4*)rp)[0], x);
    unp8(((const uint4*)rp)[1], x + 8);
    unp8(((const uint4*)rp)[2], x + 16);
    unp8(((const uint4*)rp)[3], x + 24);
    float s = 0.f;
#pragma unroll
    for (int e = 0; e < 32; ++e) s += x[e];
    s += __shfl_xor(s, 1); s += __shfl_xor(s, 2); s += __shfl_xor(s, 4);
    const float mu = s * (1.f / 256.f);
    float vs = 0.f;
#pragma unroll
    for (int e = 0; e < 32; ++e) { const float d = x[e] - mu; vs += d * d; }
    vs += __shfl_xor(vs, 1); vs += __shfl_xor(vs, 2); vs += __shfl_xor(vs, 4);
    const float rs = rsqrtf(vs * (1.f / 256.f) + 1e-5f);
#pragma unroll
    for (int c8 = 0; c8 < 4; ++c8) {
        const int cb = sub * 32 + c8 * 8;
        const float4 g0 = *(const float4*)(lng + cb), g1 = *(const float4*)(lng + cb + 4);
        const float4 b0 = *(const float4*)(lnb + cb), b1 = *(const float4*)(lnb + cb + 4);
        float4 ya, yb;
        ya.x = (x[c8*8+0]-mu)*rs*g0.x + b0.x;
        ya.y = (x[c8*8+1]-mu)*rs*g0.y + b0.y;
        ya.z = (x[c8*8+2]-mu)*rs*g0.z + b0.z;
        ya.w = (x[c8*8+3]-mu)*rs*g0.w + b0.w;
        yb.x = (x[c8*8+4]-mu)*rs*g1.x + b1.x;
        yb.y = (x[c8*8+5]-mu)*rs*g1.y + b1.y;
        yb.z = (x[c8*8+6]-mu)*rs*g1.z + b1.z;
        yb.w = (x[c8*8+7]-mu)*rs*g1.w + b1.w;
        ((uint4*)rp)[c8] = pack8(ya, yb);
    }
}

// ---------------------------------------------------------------------------
// attn_tail (R10): LN fused in; QKV split into 3 passes of acc[2][4] (32 AGPR
// peak instead of 96 -> total regs <=128 -> 4 waves/SIMD); gram loss via MFMA
// on wave 0 (diag = norms) while waves 1-3 do pool; wave-parallel logits.
// LDS 40960 B = 160K/4 -> 4 blocks/CU.
// ---------------------------------------------------------------------------
__global__ __launch_bounds__(256) void attn_tail_kernel(
    const u16* __restrict__ redb, const int* __restrict__ mask,
    const u16* __restrict__ Wqkvb,                       // [768][256]: q,k,v stacked
    const float* __restrict__ bq, const float* __restrict__ bk,
    const float* __restrict__ bv, const u16* __restrict__ Wob,
    const float* __restrict__ bo, const float* __restrict__ lng,
    const float* __restrict__ lnb, const u16* __restrict__ Wpb,
    const float* __restrict__ bp, float* __restrict__ out,
    float* __restrict__ lossAcc)
{
    __shared__ __align__(16) unsigned char SM[40960];
    u16* s_rq = (u16*)SM;                  // [23][264] h2 -> red -> q -> ctx
    u16* s_k  = (u16*)(SM + 12144);        // [23][264] k -> P -> updated
    u16* s_vT = (u16*)(SM + 24288);        // [256][32] V^T, j>=23 zero
    int* sEx   = (int*)(SM + 40672);       // [23]
    int* sMiss = (int*)(SM + 40764);       // [23]
    // tail scratch aliases the dead s_vT region:
    float* sDiag = (float*)(SM + 24288);   // [23] gram diagonal
    float* sInv  = (float*)(SM + 24384);   // [23]
    float* sPool = (float*)(SM + 24480);   // [256]

    const int b = blockIdx.x, t = threadIdx.x;
    const int w = t >> 6, lane = t & 63;
    const int frow = lane & 15, quad = lane >> 4;
    const int r0c = frow;
    const int r1c = (16 + frow > 22) ? 22 : 16 + frow;   // clamp dup rows
    const f32x4 z4 = f32x4{0.f, 0.f, 0.f, 0.f};

    // mask -> sEx/sMiss via wave-0 ballot
    {
        const int myEx = (t < 23) ? mask[b * 23 + t] : 0;
        if (t < 23) sEx[t] = myEx;
        if (t < 64) {
            const unsigned long long ball = __ballot((t < 23) && (myEx > 0));
            if (t < 23) sMiss[t] = (ball != 0ull && myEx <= 0) ? 1 : 0;
        }
    }
    // zero s_vT (j>=23 K-pad for ctx MFMA): 16384 B = 1024 uint4
    for (int i = t; i < 1024; i += 256) ((uint4*)s_vT)[i] = make_uint4(0u, 0u, 0u, 0u);
    // stage raw h2
    for (int i = t; i < 736; i += 256) {
        const int s = i >> 5, c8 = (i & 31) * 8;
        *(uint4*)(s_rq + s * QSTR + c8) =
            *(const uint4*)(redb + ((size_t)(b * 23 + s)) * 256 + c8);
    }
    __syncthreads();

    // LN in place -> red
    ln_rows_inplace(s_rq, t, lng, lnb);
    __syncthreads();

    // ---- QKV in 3 passes (k, v, then q), acc[2][4] each (32 AGPR peak) ----
    // wave w owns cols [64w, 64w+64) of each of q/k/v.
#define QKV_KLOOP(SEGBASE, ACC)                                                   \
    for (int k0 = 0; k0 < 256; k0 += 32) {                                        \
        short8 a0 = *(const short8*)(s_rq + r0c * QSTR + k0 + quad * 8);          \
        short8 a1 = *(const short8*)(s_rq + r1c * QSTR + k0 + quad * 8);          \
        _Pragma("unroll")                                                         \
        for (int nt = 0; nt < 4; ++nt) {                                          \
            const int n = (SEGBASE) + w * 64 + nt * 16 + frow;                    \
            short8 bfr = *(const short8*)(Wqkvb + (size_t)n * 256 + k0 + quad * 8); \
            ACC[0][nt] = MFMA16(a0, bfr, ACC[0][nt]);                             \
            ACC[1][nt] = MFMA16(a1, bfr, ACC[1][nt]);                             \
        }                                                                         \
    }

    {   // k-pass
        f32x4 ka[2][4];
#pragma unroll
        for (int mt = 0; mt < 2; ++mt)
#pragma unroll
            for (int nt = 0; nt < 4; ++nt) ka[mt][nt] = z4;
        QKV_KLOOP(256, ka)
#pragma unroll
        for (int nt = 0; nt < 4; ++nt) {
            const int cm = w * 64 + nt * 16 + frow;
            const float bb = bk[cm];
#pragma unroll
            for (int mt = 0; mt < 2; ++mt)
#pragma unroll
                for (int reg = 0; reg < 4; ++reg) {
                    const int s = mt * 16 + quad * 4 + reg;
                    if (s < 23) s_k[s * QSTR + cm] = fbf(ka[mt][nt][reg] + bb);
                }
        }
    }
    {   // v-pass (transposed store)
        f32x4 va[2][4];
#pragma unroll
        for (int mt = 0; mt < 2; ++mt)
#pragma unroll
            for (int nt = 0; nt < 4; ++nt) va[mt][nt] = z4;
        QKV_KLOOP(512, va)
#pragma unroll
        for (int nt = 0; nt < 4; ++nt) {
            const int cm = w * 64 + nt * 16 + frow;
            const float bb = bv[cm];
#pragma unroll
            for (int mt = 0; mt < 2; ++mt)
#pragma unroll
                for (int reg = 0; reg < 4; ++reg) {
                    const int s = mt * 16 + quad * 4 + reg;
                    if (s < 23) s_vT[cm * 32 + s] = fbf(va[mt][nt][reg] + bb);
                }
        }
    }
    {   // q-pass: acc stays live across the barrier, then overlays red
        f32x4 qa[2][4];
#pragma unroll
        for (int mt = 0; mt < 2; ++mt)
#pragma unroll
            for (int nt = 0; nt < 4; ++nt) qa[mt][nt] = z4;
        QKV_KLOOP(0, qa)
        __syncthreads();           // ALL waves done reading red
#pragma unroll
        for (int nt = 0; nt < 4; ++nt) {
            const int cm = w * 64 + nt * 16 + frow;
            const float bb = bq[cm];
#pragma unroll
            for (int mt = 0; mt < 2; ++mt)
#pragma unroll
                for (int reg = 0; reg < 4; ++reg) {
                    const int s = mt * 16 + quad * 4 + reg;
                    if (s < 23) s_rq[s * QSTR + cm] = fbf(qa[mt][nt][reg] + bb);
                }
        }
    }
    // NO barrier: scores/ctx of wave w read only cols [64w,64w+64) it wrote.

    // ---- scores (MFMA) + softmax (shfl) + P write + ctx (MFMA), wave-private ----
    {
        const float scl = 0.17677669529663687f;       // 1/sqrt(32)
        const float m0 = (sEx[frow] > 0) ? 0.f : -1e9f;
        const float m1 = (16 + frow < 23 && sEx[16 + frow] > 0) ? 0.f : -1e9f;
#pragma unroll
        for (int hh2 = 0; hh2 < 2; ++hh2) {
            const int hb = w * 64 + hh2 * 32;
            short8 aq0 = *(const short8*)(s_rq + r0c * QSTR + hb + quad * 8);
            short8 aq1 = *(const short8*)(s_rq + r1c * QSTR + hb + quad * 8);
            short8 bk0 = *(const short8*)(s_k + r0c * QSTR + hb + quad * 8);
            short8 bk1 = *(const short8*)(s_k + r1c * QSTR + hb + quad * 8);
            f32x4 s00 = MFMA16(aq0, bk0, z4);
            f32x4 s01 = MFMA16(aq0, bk1, z4);
            f32x4 s10 = MFMA16(aq1, bk0, z4);
            f32x4 s11 = MFMA16(aq1, bk1, z4);
#pragma unroll
            for (int mt = 0; mt < 2; ++mt) {
                f32x4& c0 = mt ? s10 : s00;
                f32x4& c1 = mt ? s11 : s01;
#pragma unroll
                for (int reg = 0; reg < 4; ++reg) {
                    float v0 = c0[reg] * scl + m0;
                    float v1 = c1[reg] * scl + m1;
                    float mx = fmaxf(v0, v1);
#pragma unroll
                    for (int m = 8; m; m >>= 1) mx = fmaxf(mx, __shfl_xor(mx, m));
                    float p0 = __expf(v0 - mx), p1 = __expf(v1 - mx);
                    float sm = p0 + p1;
#pragma unroll
                    for (int m = 8; m; m >>= 1) sm += __shfl_xor(sm, m);
                    const float inv = 1.f / sm;
                    c0[reg] = p0 * inv;
                    c1[reg] = p1 * inv;
                }
            }
#pragma unroll
            for (int reg = 0; reg < 4; ++reg) {
                const int q0r = quad * 4 + reg;
                s_k[q0r * QSTR + hb + frow]      = fbf(s00[reg]);
                s_k[q0r * QSTR + hb + 16 + frow] = fbf(s01[reg]);
                const int q1r = 16 + quad * 4 + reg;
                if (q1r < 23) {
                    s_k[q1r * QSTR + hb + frow]      = fbf(s10[reg]);
                    s_k[q1r * QSTR + hb + 16 + frow] = fbf(s11[reg]);
                }
            }
            short8 pa0 = *(const short8*)(s_k + r0c * QSTR + hb + quad * 8);
            short8 pa1 = *(const short8*)(s_k + r1c * QSTR + hb + quad * 8);
            short8 bv0 = *(const short8*)(s_vT + (hb + frow) * 32 + quad * 8);
            short8 bv1 = *(const short8*)(s_vT + (hb + 16 + frow) * 32 + quad * 8);
            f32x4 c00 = MFMA16(pa0, bv0, z4);
            f32x4 c01 = MFMA16(pa0, bv1, z4);
            f32x4 c10 = MFMA16(pa1, bv0, z4);
            f32x4 c11 = MFMA16(pa1, bv1, z4);
#pragma unroll
            for (int reg = 0; reg < 4; ++reg) {
                const int q0r = quad * 4 + reg;
                s_rq[q0r * QSTR + hb + frow]      = fbf(c00[reg]);
                s_rq[q0r * QSTR + hb + 16 + frow] = fbf(c01[reg]);
                const int q1r = 16 + quad * 4 + reg;
                if (q1r < 23) {
                    s_rq[q1r * QSTR + hb + frow]      = fbf(c10[reg]);
                    s_rq[q1r * QSTR + hb + 16 + frow] = fbf(c11[reg]);
                }
            }
        }
    }
    __syncthreads();   // ctx (in s_rq) visible to all

    // ---- Wo via MFMA; restage h2 (issued early), LN, assemble updated ----
    {
        // issue restage loads early (hide under Wo k-loop)
        const u16* src = redb + (size_t)(b * 23) * 256;
        const int s0 = t >> 5, c0o = (t & 31) * 8;
        uint4 rg0 = *(const uint4*)(src + s0 * 256 + c0o);
        uint4 rg1 = *(const uint4*)(src + (s0 + 8) * 256 + c0o);
        uint4 rg2;
        const bool has2 = (t + 512) < 736;
        if (has2) rg2 = *(const uint4*)(src + (s0 + 16) * 256 + c0o);

        f32x4 wacc[2][4];
#pragma unroll
        for (int mt = 0; mt < 2; ++mt)
#pragma unroll
            for (int nt = 0; nt < 4; ++nt) wacc[mt][nt] = z4;
        for (int k0 = 0; k0 < 256; k0 += 32) {
            short8 a0 = *(const short8*)(s_rq + r0c * QSTR + k0 + quad * 8);
            short8 a1 = *(const short8*)(s_rq + r1c * QSTR + k0 + quad * 8);
#pragma unroll
            for (int nt = 0; nt < 4; ++nt) {
                const int n = w * 64 + nt * 16 + frow;
                short8 bfr = *(const short8*)(Wob + (size_t)n * 256 + k0 + quad * 8);
                wacc[0][nt] = MFMA16(a0, bfr, wacc[0][nt]);
                wacc[1][nt] = MFMA16(a1, bfr, wacc[1][nt]);
            }
        }
        // write restaged h2 into s_k (P dead)
        *(uint4*)(s_k + s0 * QSTR + c0o) = rg0;
        *(uint4*)(s_k + (s0 + 8) * QSTR + c0o) = rg1;
        if (has2) *(uint4*)(s_k + (s0 + 16) * QSTR + c0o) = rg2;
        __syncthreads();
        ln_rows_inplace(s_k, t, lng, lnb);   // red for existing rows
        __syncthreads();
        // missing rows: overwrite with mha_out = wacc + bo (own cols)
#pragma unroll
        for (int nt = 0; nt < 4; ++nt) {
            const int col = w * 64 + nt * 16 + frow;
            const float bvv = bo[col];
#pragma unroll
            for (int mt = 0; mt < 2; ++mt)
#pragma unroll
                for (int reg = 0; reg < 4; ++reg) {
                    const int s = mt * 16 + quad * 4 + reg;
                    if (s < 23 && sMiss[s])
                        s_k[s * QSTR + col] = fbf(wacc[mt][nt][reg] + bvv);
                }
        }
    }
    __syncthreads();   // s_k = updated [23][256]

    // ---- tail: gram via MFMA on wave 0 (diag = norms); pool on waves 1-3 ----
    f32x4 g00 = z4, g01 = z4, g10 = z4, g11 = z4;
    if (w == 0) {
        for (int k0 = 0; k0 < 256; k0 += 32) {
            short8 a0 = *(const short8*)(s_k + r0c * QSTR + k0 + quad * 8);
            short8 a1 = *(const short8*)(s_k + r1c * QSTR + k0 + quad * 8);
            g00 = MFMA16(a0, a0, g00);
            g01 = MFMA16(a0, a1, g01);
            g10 = MFMA16(a1, a0, g10);
            g11 = MFMA16(a1, a1, g11);
        }
#pragma unroll
        for (int reg = 0; reg < 4; ++reg) {
            if (frow == quad * 4 + reg) {
                sDiag[frow] = g00[reg];
                if (16 + frow < 23) sDiag[16 + frow] = g11[reg];
            }
        }
    } else {
        for (int c = t - 64; c < 256; c += 192) {
            float pv = 0.f;
#pragma unroll
            for (int s = 0; s < 23; ++s) pv += bf1(s_k[s * QSTR + c]);
            sPool[c] = pv * (1.f / 23.f);
        }
    }
    __syncthreads();
    if (t < 23) sInv[t] = 1.f / fmaxf(sqrtf(sDiag[t]), 1e-8f);
    __syncthreads();

    if (w == 0) {
        // margin loss from gram tiles (each ordered pair once)
        float contrib = 0.f;
        const float ic0 = sInv[frow];
        const float ic1 = (16 + frow < 23) ? sInv[16 + frow] : 0.f;
        const bool c1ok = (16 + frow < 23);
#pragma unroll
        for (int reg = 0; reg < 4; ++reg) {
            const int rA = quad * 4 + reg;          // < 16
            const float irA = sInv[rA];
            if (rA != frow) {
                const float cc = fabsf(g00[reg] * irA * ic0) - 0.1f;
                if (cc > 0.f) contrib += cc;
            }
            if (c1ok) {
                const float cc = fabsf(g01[reg] * irA * ic1) - 0.1f;
                if (cc > 0.f) contrib += cc;
            }
            const int rB = 16 + quad * 4 + reg;
            if (rB < 23) {
                const float irB = sInv[rB];
                {
                    const float cc = fabsf(g10[reg] * irB * ic0) - 0.1f;
                    if (cc > 0.f) contrib += cc;
                }
                if (c1ok && rB != 16 + frow) {
                    const float cc = fabsf(g11[reg] * irB * ic1) - 0.1f;
                    if (cc > 0.f) contrib += cc;
                }
            }
        }
#pragma unroll
        for (int m = 32; m; m >>= 1) contrib += __shfl_xor(contrib, m);
        if (lane == 0) atomicAdd(lossAcc, contrib);
    } else {
        // logits: 8 lanes per label; waves 1-3 cover labels 0..23, then 24.
        const int li = t - 64;
#pragma unroll 1
        for (int pass = 0; pass < 2; ++pass) {
            int L, chunk;
            if (pass == 0) { L = li >> 3; chunk = li & 7; }
            else { if (li >= 8) break; L = 24; chunk = li; }
            float a = 0.f;
#pragma unroll
            for (int q4 = 0; q4 < 4; ++q4) {
                const int c8 = chunk * 4 + q4;
                float wf[8]; unp8(*(const uint4*)(Wpb + (size_t)L * 256 + c8 * 8), wf);
                const float4 p0 = *(const float4*)(sPool + c8 * 8);
                const float4 p1 = *(const float4*)(sPool + c8 * 8 + 4);
                a += wf[0] * p0.x + wf[1] * p0.y + wf[2] * p0.z + wf[3] * p0.w
                   + wf[4] * p1.x + wf[5] * p1.y + wf[6] * p1.z + wf[7] * p1.w;
            }
            a += __shfl_xor(a, 1); a += __shfl_xor(a, 2); a += __shfl_xor(a, 4);
            if (chunk == 0) out[1 + b * 25 + L] = a + bp[L];
        }
    }
}

__global__ void loss_finalize(const float* __restrict__ lossAcc, float* __restrict__ out)
{
    out[0] = lossAcc[0] * (1.f / 1036288.f);   // B*S*(S-1) = 2048*23*22
}

// ---------------------------------------------------------------------------
extern "C" void kernel_launch(void* const* d_in, const int* in_sizes, int n_in,
                              void* d_out, int out_size, void* d_ws, size_t ws_size,
                              hipStream_t stream)
{
    const float* cls     = (const float*)d_in[0];
    const int*   mask    = (const int*)d_in[1];
    const float* missing = (const float*)d_in[2];
    const float* W1 = (const float*)d_in[3];  const float* b1 = (const float*)d_in[4];
    const float* W2 = (const float*)d_in[5];  const float* b2 = (const float*)d_in[6];
    const float* lng = (const float*)d_in[7]; const float* lnb = (const float*)d_in[8];
    const float* Wq = (const float*)d_in[9];  const float* bq = (const float*)d_in[10];
    const float* Wk = (const float*)d_in[11]; const float* bk = (const float*)d_in[12];
    const float* Wv = (const float*)d_in[13]; const float* bv = (const float*)d_in[14];
    const float* Wo = (const float*)d_in[15]; const float* bo = (const float*)d_in[16];
    const float* Wp = (const float*)d_in[17]; const float* bp = (const float*)d_in[18];
    float* out = (float*)d_out;

    char* ws = (char*)d_ws;
    u16* h1b  = (u16*)ws;                         // [47104x384]
    u16* redb = (u16*)(ws + 36175872);            // [47104x256] h2 (pre-LN)
    u16* Wb   = (u16*)(ws + 60293120);            // bf16 weights (661,760 elems)
    u16* W1b   = Wb;
    u16* W2b   = Wb + 294912;
    u16* Wqkvb = Wb + 393216;                     // q,k,v contiguous [768][256]
    u16* Wob   = Wb + 589824;
    u16* Wpb   = Wb + 655360;
    float* lossAcc = (float*)(ws + 61616640);

    hipMemsetAsync(lossAcc, 0, sizeof(float), stream);

    wconv<<<2585, 256, 0, stream>>>(W1, W2, Wq, Wk, Wv, Wo, Wp, Wb);
    // h1 = gelu(gather(cls,missing,mask) @ W1^T + b1)
    gemm1_kernel<<<dim3(3, 368), 256, 0, stream>>>(cls, mask, missing, W1b, b1, h1b);
    // h2 = gelu(h1 @ W2^T + b2) -> redb (pre-LN; LN fused into attn_tail)
    gemm_bt<<<dim3(2, 368), 256, 0, stream>>>(h1b, W2b, b2, redb, 384, 256);
    // fused: LN + QKV + attention + Wo + updated + gram loss + pool + logits
    attn_tail_kernel<<<2048, 256, 0, stream>>>(redb, mask, Wqkvb, bq, bk, bv,
                                               Wob, bo, lng, lnb, Wpb, bp,
                                               out, lossAcc);
    loss_finalize<<<1, 1, 0, stream>>>(lossAcc, out);
}